// Round 5
// baseline (889.950 us; speedup 1.0000x reference)
//
#include <hip/hip_runtime.h>
#include <hip/hip_bf16.h>

typedef unsigned short u16;
typedef unsigned long long u64;
typedef float f32x4 __attribute__((ext_vector_type(4)));
typedef short s16x8 __attribute__((ext_vector_type(8)));

__device__ __forceinline__ float b2f(u16 u) {
    unsigned int x = ((unsigned int)u) << 16;
    return __builtin_bit_cast(float, x);
}
__device__ __forceinline__ u16 f2b(float f) {
    unsigned int x = __builtin_bit_cast(unsigned int, f);
    unsigned int lsb = (x >> 16) & 1u;
    x += 0x7fffu + lsb;                 // RNE; inputs are finite
    return (u16)(x >> 16);
}

#define GLOAD_LDS(g, l) __builtin_amdgcn_global_load_lds( \
    (const __attribute__((address_space(1))) void*)(g),   \
    (__attribute__((address_space(3))) void*)(l), 16, 0, 0)

// ---------------------------------------------------------------------------
// Batched GEMM: C[z,m,n] = sum_k A[z,m,k] * B[z,n,k]   (B stored [N][K])
// Tile 128xTN, BK=32, 256 threads = 4 waves, mfma_f32_16x16x32_bf16.
// Depth-2 pipeline: 3 LDS buffers, counted s_waitcnt vmcnt(3) + raw s_barrier
// (loads for tile t+1 stay in flight across the barrier; 3 gloads per stage).
// Swapped-operand MFMA: acc[i][j][r] = C[m = wm+i*16+l15][n = wn+j*16+lg*4+r]
// so reg index r runs along columns -> packed 8B/16B stores.
// EPI: 0 Cf=acc                      2 Cb=relu(acc+Cf+bias)
//      3 Cb=relu(acc+bias)*mask      4 Cb=acc*mask[row]*mask[col]
//      5 Cb=acc                      6 Cb=2*acc - prev2
// ---------------------------------------------------------------------------
template<int EPI, int TN>
__global__ __launch_bounds__(256)
void gemm_bt(const u16* __restrict__ A, const u16* __restrict__ B,
             float* __restrict__ Cf, u16* __restrict__ Cb,
             const float* __restrict__ bias, int biasBStride,
             const float* __restrict__ mask,
             const u16* __restrict__ prev2, int ldp, long pBS,
             int M, int N, int K, int lda, int ldb, int ldc,
             long aBS, long bBS, long cBS)
{
    constexpr int NJ = (TN == 128) ? 4 : 2;
    __shared__ u16 As[3][128 * 32];
    __shared__ u16 Bs[3][TN * 32];
    const int tid  = threadIdx.x;
    const int lane = tid & 63;
    const int z    = blockIdx.z;
    const int m0   = blockIdx.y * 128;
    const int n0   = blockIdx.x * TN;
    const int wm   = ((tid >> 7) & 1) * 64;
    const int wn   = ((tid >> 6) & 1) * (TN / 2);
    const int l15  = lane & 15;
    const int lg   = lane >> 4;
    const u16* Ab = A + (long)z * aBS;
    const u16* Bb = B + (long)z * bBS;

    f32x4 acc[4][NJ] = {};
    const int nt = K >> 5;

    auto stage = [&](int s, int t) {
        const int u0 = tid, u1 = tid + 256;
        GLOAD_LDS(Ab + (long)(m0 + (u0 >> 2)) * lda + t * 32 + (u0 & 3) * 8, &As[s][u0 * 8]);
        GLOAD_LDS(Ab + (long)(m0 + (u1 >> 2)) * lda + t * 32 + (u1 & 3) * 8, &As[s][u1 * 8]);
        GLOAD_LDS(Bb + (long)(n0 + (u0 >> 2)) * ldb + t * 32 + (u0 & 3) * 8, &Bs[s][u0 * 8]);
        if (TN == 128)
            GLOAD_LDS(Bb + (long)(n0 + (u1 >> 2)) * ldb + t * 32 + (u1 & 3) * 8, &Bs[s][u1 * 8]);
    };

    stage(0, 0);
    if (nt > 1) stage(1, 1);
    int cur = 0;
    for (int t = 0; t < nt; ++t) {
        // stage(t) must be complete; stage(t+1)'s loads (3 per thread) may
        // remain in flight across the barrier. Last iter: drain all.
        if (t + 1 < nt) {
            if (TN == 128) asm volatile("s_waitcnt vmcnt(4) lgkmcnt(0)" ::: "memory");
            else           asm volatile("s_waitcnt vmcnt(3) lgkmcnt(0)" ::: "memory");
        } else {
            asm volatile("s_waitcnt vmcnt(0) lgkmcnt(0)" ::: "memory");
        }
        __builtin_amdgcn_s_barrier();
        s16x8 af[4], bg[NJ];
        #pragma unroll
        for (int i = 0; i < 4; ++i)
            af[i] = *(const s16x8*)&As[cur][(wm + i * 16 + l15) * 32 + lg * 8];
        #pragma unroll
        for (int j = 0; j < NJ; ++j)
            bg[j] = *(const s16x8*)&Bs[cur][(wn + j * 16 + l15) * 32 + lg * 8];
        if (t + 2 < nt) stage(cur == 0 ? 2 : cur - 1, t + 2);  // (cur+2)%3
        #pragma unroll
        for (int i = 0; i < 4; ++i)
            #pragma unroll
            for (int j = 0; j < NJ; ++j)
                acc[i][j] = __builtin_amdgcn_mfma_f32_16x16x32_bf16(bg[j], af[i], acc[i][j], 0, 0, 0);
        cur = (cur == 2) ? 0 : cur + 1;
    }

    const long cb0 = (long)z * cBS;
    #pragma unroll
    for (int i = 0; i < 4; ++i) {
        const int row = m0 + wm + i * 16 + l15;
        float rm = 1.f;
        if ((EPI == 3 || EPI == 4) && mask) rm = mask[z * M + row];
        #pragma unroll
        for (int j = 0; j < NJ; ++j) {
            const int nb = n0 + wn + j * 16 + lg * 4;
            if (nb >= N) continue;
            const long idx = cb0 + (long)row * ldc + nb;
            if (EPI == 0) {
                *(float4*)&Cf[idx] = make_float4(acc[i][j][0], acc[i][j][1], acc[i][j][2], acc[i][j][3]);
            } else {
                float x[4];
                if (EPI == 2) {
                    const float4 cv = *(const float4*)&Cf[idx];
                    x[0] = fmaxf(acc[i][j][0] + cv.x + bias[nb + 0], 0.f);
                    x[1] = fmaxf(acc[i][j][1] + cv.y + bias[nb + 1], 0.f);
                    x[2] = fmaxf(acc[i][j][2] + cv.z + bias[nb + 2], 0.f);
                    x[3] = fmaxf(acc[i][j][3] + cv.w + bias[nb + 3], 0.f);
                } else if (EPI == 3) {
                    const int bb0 = biasBStride ? ((z * M + row) >> 10) * biasBStride : 0;
                    #pragma unroll
                    for (int r = 0; r < 4; ++r) {
                        float v = fmaxf(acc[i][j][r] + bias[bb0 + nb + r], 0.f);
                        x[r] = mask ? v * rm : v;
                    }
                } else if (EPI == 4) {
                    #pragma unroll
                    for (int r = 0; r < 4; ++r)
                        x[r] = acc[i][j][r] * rm * mask[z * N + nb + r];
                } else if (EPI == 5) {
                    #pragma unroll
                    for (int r = 0; r < 4; ++r) x[r] = acc[i][j][r];
                } else {
                    const u64 pv = *(const u64*)&prev2[(long)z * pBS + (long)row * ldp + nb];
                    #pragma unroll
                    for (int r = 0; r < 4; ++r)
                        x[r] = 2.f * acc[i][j][r] - b2f((u16)(pv >> (16 * r)));
                }
                u64 pk = (u64)f2b(x[0]) | ((u64)f2b(x[1]) << 16)
                       | ((u64)f2b(x[2]) << 32) | ((u64)f2b(x[3]) << 48);
                *(u64*)&Cb[idx] = pk;
            }
        }
    }
}

// fp32 [K][N] -> bf16 [n][ldD] transpose+convert, zero pad for k in [K,Kpad)
__global__ void cvtT_k(const float* __restrict__ src, u16* __restrict__ dst,
                       int K, int N, int Kpad, int ldD, long sBS, long dBS)
{
    __shared__ float t[32][33];
    const int tx = threadIdx.x, ty = threadIdx.y;
    const int k0 = blockIdx.x * 32, n0 = blockIdx.y * 32;
    src += (long)blockIdx.z * sBS;
    dst += (long)blockIdx.z * dBS;
    #pragma unroll
    for (int rr = ty; rr < 32; rr += 8) {
        int k = k0 + rr, n = n0 + tx;
        t[rr][tx] = (k < K && n < N) ? src[(long)k * N + n] : 0.f;
    }
    __syncthreads();
    #pragma unroll
    for (int rr = ty; rr < 32; rr += 8) {
        int n = n0 + rr, k = k0 + tx;
        if (n < N && k < Kpad) dst[(long)n * ldD + k] = f2b(t[tx][rr]);
    }
}

// bf16 [R][C] (row stride lds_) -> bf16 [C][R] (row stride ldd_), batched
__global__ void tranb_k(const u16* __restrict__ src, u16* __restrict__ dst,
                        int lds_, int ldd_, long sBS, long dBS)
{
    __shared__ u16 t[32][33];
    const int tx = threadIdx.x, ty = threadIdx.y;
    const int r0 = blockIdx.y * 32, c0 = blockIdx.x * 32;
    src += (long)blockIdx.z * sBS;
    dst += (long)blockIdx.z * dBS;
    #pragma unroll
    for (int rr = ty; rr < 32; rr += 8)
        t[rr][tx] = src[(long)(r0 + rr) * lds_ + c0 + tx];
    __syncthreads();
    #pragma unroll
    for (int rr = ty; rr < 32; rr += 8)
        dst[(long)(c0 + rr) * ldd_ + r0 + tx] = t[tx][rr];
}

__global__ void cvt_k(const float* __restrict__ src, u16* __restrict__ dst, int n)
{
    for (long i = (long)(blockIdx.x * 256 + threadIdx.x) * 4; i < n; i += (long)gridDim.x * 1024) {
        float4 v = *(const float4*)&src[i];
        u64 pk = (u64)f2b(v.x) | ((u64)f2b(v.y) << 16)
               | ((u64)f2b(v.z) << 32) | ((u64)f2b(v.w) << 48);
        *(u64*)&dst[i] = pk;
    }
}

__global__ void mask_k(const float* __restrict__ inp, float* __restrict__ mask)
{
    const int row = blockIdx.x, tid = threadIdx.x;
    float4 v = *(const float4*)&inp[(long)row * 1024 + tid * 4];
    float s = v.x + v.y + v.z + v.w;
    __shared__ float red[256];
    red[tid] = s; __syncthreads();
    for (int o = 128; o > 0; o >>= 1) { if (tid < o) red[tid] += red[tid + o]; __syncthreads(); }
    if (tid == 0) mask[row] = (red[0] != 0.f) ? 1.f : 0.f;
}

// fused: numel + masked column mean + c = relu(mean@Wc+bc) + cb = ba1 + c@Wa1[512:]
// grid 8 (one block per batch), 512 threads
__global__ void cvec_fused_k(const u16* __restrict__ fea, const float* __restrict__ mask,
                             const float* __restrict__ Wc, const float* __restrict__ bc,
                             const float* __restrict__ Wa1, const float* __restrict__ ba1,
                             float* __restrict__ cb)
{
    const int b = blockIdx.x, tid = threadIdx.x;
    __shared__ float mean[512];
    __shared__ float red[512];
    __shared__ float cC[128];
    // column sum over 1024 nodes (fea already mask-multiplied)
    const u16* p = fea + (long)b * 1024 * 512 + tid;
    float s = 0.f;
    #pragma unroll 4
    for (int n = 0; n < 1024; ++n) s += b2f(p[(long)n * 512]);
    // numel
    red[tid] = mask[b * 1024 + tid] + mask[b * 1024 + 512 + tid];
    __syncthreads();
    for (int o = 256; o > 0; o >>= 1) { if (tid < o) red[tid] += red[tid + o]; __syncthreads(); }
    const float numel = red[0];
    __syncthreads();
    mean[tid] = s / numel;
    __syncthreads();
    // c = relu(mean @ Wc + bc), 4-way f-split
    const int o = tid & 127, q = tid >> 7;
    float cs = 0.f;
    for (int f = q * 128; f < q * 128 + 128; ++f) cs += mean[f] * Wc[f * 128 + o];
    red[tid] = cs;
    __syncthreads();
    if (tid < 256) red[tid] += red[tid + 256];
    __syncthreads();
    if (tid < 128) cC[tid] = fmaxf(red[tid] + red[tid + 128] + bc[tid], 0.f);
    __syncthreads();
    // cb[b][o2] = ba1[o2] + sum_j c[j] * Wa1[512+j][o2]
    float t = ba1[tid];
    for (int jj = 0; jj < 128; ++jj) t += cC[jj] * Wa1[(512 + jj) * 512 + tid];
    cb[b * 512 + tid] = t;
}

__global__ void dinv_k(const u16* __restrict__ Abf, float* __restrict__ dinv)
{
    const int row = blockIdx.x, tid = threadIdx.x;
    const u16* p = Abf + (long)row * 1024 + tid * 4;
    float s = b2f(p[0]) + b2f(p[1]) + b2f(p[2]) + b2f(p[3]);
    __shared__ float red[256];
    red[tid] = s; __syncthreads();
    for (int o = 128; o > 0; o >>= 1) { if (tid < o) red[tid] += red[tid + o]; __syncthreads(); }
    if (tid == 0) {
        float d = red[0];
        dinv[row] = d > 0.f ? rsqrtf(fmaxf(d, 1e-30f)) : 0.f;
    }
}

__global__ void lhat_k(u16* __restrict__ Abf, const float* __restrict__ dinv)
{
    const long e0 = ((long)blockIdx.x * 256 + threadIdx.x) * 4;
    const int b = (int)(e0 >> 20);
    const int i = (int)((e0 >> 10) & 1023);
    const int j = (int)(e0 & 1023);
    const float di = dinv[b * 1024 + i];
    u16* p = Abf + e0;
    #pragma unroll
    for (int t = 0; t < 4; ++t) {
        float v = -di * b2f(p[t]) * dinv[b * 1024 + j + t];
        p[t] = f2b(v);
    }
}

// fused pooling tail: gate -> softmax -> weighted sum -> output MLP -> sigmoid
// grid 8 (one block per batch), 512 threads
__global__ void pool_fused_k(const u16* __restrict__ g2, const float* __restrict__ Wp3,
                             const float* __restrict__ bp3, const float* __restrict__ mask,
                             const u16* __restrict__ x2,
                             const float* __restrict__ Wm1, const float* __restrict__ bm1,
                             const float* __restrict__ Wm2, const float* __restrict__ bm2,
                             float* __restrict__ out)
{
    const int b = blockIdx.x, tid = threadIdx.x;
    __shared__ float att[1024];
    __shared__ float red[512];
    __shared__ float pooled[384];
    __shared__ float wp3[64];
    if (tid < 64) wp3[tid] = Wp3[tid];
    __syncthreads();
    // phase 1: gates (tanh of 64-dot), masked
    #pragma unroll
    for (int r = tid; r < 1024; r += 512) {
        const s16x8* g = (const s16x8*)(g2 + ((long)b * 1024 + r) * 64);
        float s = 0.f;
        #pragma unroll
        for (int c8 = 0; c8 < 8; ++c8) {
            s16x8 v = g[c8];
            #pragma unroll
            for (int jj = 0; jj < 8; ++jj) s += b2f((u16)v[jj]) * wp3[c8 * 8 + jj];
        }
        att[r] = (mask[b * 1024 + r] > 0.f) ? tanhf(s + bp3[0]) : -1e9f;
    }
    __syncthreads();
    // phase 2: softmax over 1024
    red[tid] = fmaxf(att[tid], att[tid + 512]);
    __syncthreads();
    for (int o = 256; o > 0; o >>= 1) { if (tid < o) red[tid] = fmaxf(red[tid], red[tid + o]); __syncthreads(); }
    const float mx = red[0];
    __syncthreads();
    float e0 = expf(att[tid] - mx), e1 = expf(att[tid + 512] - mx);
    att[tid] = e0; att[tid + 512] = e1;
    red[tid] = e0 + e1;
    __syncthreads();
    for (int o = 256; o > 0; o >>= 1) { if (tid < o) red[tid] += red[tid + o]; __syncthreads(); }
    const float zi = 1.f / red[0];
    __syncthreads();
    // phase 3: pooled[o] = sum_n att[n]*x2[b,n,o] * zi
    for (int o = tid; o < 384; o += 512) {
        const u16* xb = x2 + (long)b * 1024 * 384 + o;
        float s = 0.f;
        #pragma unroll 4
        for (int n = 0; n < 1024; ++n) s += att[n] * b2f(xb[(long)n * 384]);
        pooled[o] = s * zi;
    }
    __syncthreads();
    // phase 4: out = sigmoid(relu(pooled@Wm1+bm1)@Wm2+bm2)
    if (tid < 256) {
        float s = bm1[tid];
        for (int f = 0; f < 384; ++f) s += pooled[f] * Wm1[f * 256 + tid];
        float h = fmaxf(s, 0.f) * Wm2[tid];
        for (int off = 32; off > 0; off >>= 1) h += __shfl_xor(h, off, 64);
        if ((tid & 63) == 0) red[tid >> 6] = h;
    }
    __syncthreads();
    if (tid == 0)
        out[b] = 1.f / (1.f + expf(-(red[0] + red[1] + red[2] + red[3] + bm2[0])));
}

// ---------------------------------------------------------------------------
// workspace layout
// ---------------------------------------------------------------------------
constexpr size_t OFS_WF1T = 0;                               // 832x1024 bf16
constexpr size_t OFS_WF2T = OFS_WF1T + 832ull * 1024 * 2;    // 512x800
constexpr size_t OFS_WF3T = OFS_WF2T + 512ull * 800 * 2;     // 512x512
constexpr size_t OFS_WA1T = OFS_WF3T + 512ull * 512 * 2;
constexpr size_t OFS_WA2T = OFS_WA1T + 512ull * 512 * 2;     // 384x512
constexpr size_t OFS_WG1T0 = OFS_WA2T + 384ull * 512 * 2;    // 512x512
constexpr size_t OFS_WG1C  = OFS_WG1T0 + 512ull * 512 * 2;   // 512x2048
constexpr size_t OFS_WG2T0 = OFS_WG1C + 512ull * 2048 * 2;   // 384x512
constexpr size_t OFS_WG2C  = OFS_WG2T0 + 384ull * 512 * 2;   // 384x2048
constexpr size_t OFS_WP1T  = OFS_WG2C + 384ull * 2048 * 2;   // 128x384
constexpr size_t OFS_WP2T  = OFS_WP1T + 128ull * 384 * 2;    // 64x128
constexpr size_t OFS_MASK  = OFS_WP2T + 64ull * 128 * 2;
constexpr size_t OFS_CB    = OFS_MASK + 32768;
constexpr size_t OFS_DINV  = OFS_CB + 16384;
constexpr size_t OFS_RA    = OFS_DINV + 32768;               // 16 MiB: xbf | a1,a2 | facc
constexpr size_t OFS_RB    = OFS_RA + 16777216;              // 12.5 MiB: h1 | tt
constexpr size_t OFS_RC    = OFS_RB + 13107200;              // 8 MiB: h2 | x1 | g1,g2
constexpr size_t OFS_RD    = OFS_RC + 8388608;               // 8 MiB: fea | x2
constexpr size_t OFS_RE    = OFS_RD + 8388608;               // 16 MiB: abf (Lhat)
constexpr size_t OFS_RF    = OFS_RE + 16777216;              // 32 MiB: Tcat (T1..T4)
constexpr size_t WS_TOTAL  = OFS_RF + 33554432;              // ~100.8 MiB

extern "C" void kernel_launch(void* const* d_in, const int* in_sizes, int n_in,
                              void* d_out, int out_size, void* d_ws, size_t ws_size,
                              hipStream_t stream)
{
    const float* inp = (const float*)d_in[0];
    const float* Wf1 = (const float*)d_in[2];  const float* bf1 = (const float*)d_in[3];
    const float* Wf2 = (const float*)d_in[4];  const float* bf2 = (const float*)d_in[5];
    const float* Wf3 = (const float*)d_in[6];  const float* bf3 = (const float*)d_in[7];
    const float* Wc  = (const float*)d_in[8];  const float* bc  = (const float*)d_in[9];
    const float* Wa1 = (const float*)d_in[10]; const float* ba1 = (const float*)d_in[11];
    const float* Wa2 = (const float*)d_in[12]; const float* ba2 = (const float*)d_in[13];
    const float* Wg1 = (const float*)d_in[14]; const float* bg1 = (const float*)d_in[15];
    const float* Wg2 = (const float*)d_in[16]; const float* bg2 = (const float*)d_in[17];
    const float* Wp1 = (const float*)d_in[18]; const float* bp1 = (const float*)d_in[19];
    const float* Wp2 = (const float*)d_in[20]; const float* bp2 = (const float*)d_in[21];
    const float* Wp3 = (const float*)d_in[22]; const float* bp3 = (const float*)d_in[23];
    const float* Wm1 = (const float*)d_in[24]; const float* bm1 = (const float*)d_in[25];
    const float* Wm2 = (const float*)d_in[26]; const float* bm2 = (const float*)d_in[27];

    if (ws_size < WS_TOTAL) return;
    char* ws = (char*)d_ws;

    u16* wf1t  = (u16*)(ws + OFS_WF1T);
    u16* wf2t  = (u16*)(ws + OFS_WF2T);
    u16* wf3t  = (u16*)(ws + OFS_WF3T);
    u16* wa1t  = (u16*)(ws + OFS_WA1T);
    u16* wa2t  = (u16*)(ws + OFS_WA2T);
    u16* wg1t0 = (u16*)(ws + OFS_WG1T0);
    u16* wg1c  = (u16*)(ws + OFS_WG1C);
    u16* wg2t0 = (u16*)(ws + OFS_WG2T0);
    u16* wg2c  = (u16*)(ws + OFS_WG2C);
    u16* wp1t  = (u16*)(ws + OFS_WP1T);
    u16* wp2t  = (u16*)(ws + OFS_WP2T);
    float* maskv   = (float*)(ws + OFS_MASK);
    float* cbv     = (float*)(ws + OFS_CB);
    float* dinvv   = (float*)(ws + OFS_DINV);

    u16*   xbf  = (u16*)(ws + OFS_RA);
    u16*   a1b  = (u16*)(ws + OFS_RA);                 // after f1
    u16*   a2b  = (u16*)(ws + OFS_RA + 8388608);
    float* facc = (float*)(ws + OFS_RA);               // after adjm
    u16*   h1   = (u16*)(ws + OFS_RB);
    u16*   tt   = (u16*)(ws + OFS_RB);                 // after f2
    u16*   h2   = (u16*)(ws + OFS_RC);
    u16*   x1   = (u16*)(ws + OFS_RC);                 // after f3
    u16*   g1   = (u16*)(ws + OFS_RC);                 // after cheb2
    u16*   g2   = (u16*)(ws + OFS_RC + 2097152);
    u16*   fea  = (u16*)(ws + OFS_RD);
    u16*   x2   = (u16*)(ws + OFS_RD);                 // after cheb1
    u16*   abf  = (u16*)(ws + OFS_RE);
    u16*   tcat = (u16*)(ws + OFS_RF);                 // [8192][2048] = T1..T4

    const dim3 tblk(32, 8);

    // weights: fp32 [K][N] -> bf16 [N][ld] (B^T layout for gemm_bt)
    cvtT_k<<<dim3(32, 25, 1), tblk, 0, stream>>>(Wf1, wf1t, 1024, 784, 1024, 1024, 0, 0);
    cvtT_k<<<dim3(25, 16, 1), tblk, 0, stream>>>(Wf2, wf2t, 784, 512, 800, 800, 0, 0);
    cvtT_k<<<dim3(16, 16, 1), tblk, 0, stream>>>(Wf3, wf3t, 512, 512, 512, 512, 0, 0);
    cvtT_k<<<dim3(16, 16, 1), tblk, 0, stream>>>(Wa1, wa1t, 512, 512, 512, 512, 0, 0);
    cvtT_k<<<dim3(16, 12, 1), tblk, 0, stream>>>(Wa2, wa2t, 512, 384, 512, 512, 0, 0);
    cvtT_k<<<dim3(16, 16, 1), tblk, 0, stream>>>(Wg1, wg1t0, 512, 512, 512, 512, 0, 0);
    cvtT_k<<<dim3(16, 16, 4), tblk, 0, stream>>>(Wg1 + 262144, wg1c, 512, 512, 512, 2048, 262144, 512);
    cvtT_k<<<dim3(16, 12, 1), tblk, 0, stream>>>(Wg2, wg2t0, 512, 384, 512, 512, 0, 0);
    cvtT_k<<<dim3(16, 12, 4), tblk, 0, stream>>>(Wg2 + 196608, wg2c, 512, 384, 512, 2048, 196608, 512);
    cvtT_k<<<dim3(12, 4, 1),  tblk, 0, stream>>>(Wp1, wp1t, 384, 128, 384, 384, 0, 0);
    cvtT_k<<<dim3(4, 2, 1),   tblk, 0, stream>>>(Wp2, wp2t, 128, 64, 128, 128, 0, 0);

    cvt_k<<<4096, 256, 0, stream>>>(inp, xbf, 8 * 1024 * 1024);
    mask_k<<<8192, 256, 0, stream>>>(inp, maskv);

    // fe_extrator
    gemm_bt<3, 64><<<dim3(13, 64, 1), 256, 0, stream>>>(xbf, wf1t, nullptr, h1, bf1, 0, maskv,
        nullptr, 0, 0, 8192, 784, 1024, 1024, 1024, 800, 0, 0, 0);
    gemm_bt<3, 64><<<dim3(8, 64, 1), 256, 0, stream>>>(h1, wf2t, nullptr, h2, bf2, 0, maskv,
        nullptr, 0, 0, 8192, 512, 800, 800, 800, 512, 0, 0, 0);
    gemm_bt<3, 64><<<dim3(8, 64, 1), 256, 0, stream>>>(h2, wf3t, nullptr, fea, bf3, 0, maskv,
        nullptr, 0, 0, 8192, 512, 512, 512, 512, 512, 0, 0, 0);

    // c vector + per-batch bias for adj layer 1 (fused)
    cvec_fused_k<<<8, 512, 0, stream>>>(fea, maskv, Wc, bc, Wa1, ba1, cbv);

    // adj net
    gemm_bt<3, 64><<<dim3(8, 64, 1), 256, 0, stream>>>(fea, wa1t, nullptr, a1b, cbv, 512, maskv,
        nullptr, 0, 0, 8192, 512, 512, 512, 512, 512, 0, 0, 0);
    gemm_bt<3, 64><<<dim3(6, 64, 1), 256, 0, stream>>>(a1b, wa2t, nullptr, a2b, ba2, 0, maskv,
        nullptr, 0, 0, 8192, 384, 512, 512, 512, 384, 0, 0, 0);

    // adjacency, degree, Lhat (in place)
    gemm_bt<4, 64><<<dim3(16, 8, 8), 256, 0, stream>>>(a2b, a2b, nullptr, abf, nullptr, 0, maskv,
        nullptr, 0, 0, 1024, 1024, 384, 384, 384, 1024, 393216, 393216, 1048576);
    dinv_k<<<8192, 256, 0, stream>>>(abf, dinvv);
    lhat_k<<<8192, 256, 0, stream>>>(abf, dinvv);

    // ChebConv: T0 separate, T1..T4 K-concat in tcat; out = T0@W0 + Tcat@Wcat + b
    auto cheb = [&](const u16* T0, const u16* W0, const u16* Wcat, int Wn,
                    const float* bias, u16* outb, float* fa) {
        const dim3 gL(8, 8, 8);
        const dim3 gTf(16, 32, 8);
        // tt = T0^T
        tranb_k<<<gTf, tblk, 0, stream>>>(T0, tt, 512, 1024, 524288, 524288);
        // T1 = Lhat @ T0
        gemm_bt<5, 64><<<gL, 256, 0, stream>>>(abf, tt, nullptr, tcat, nullptr, 0, nullptr,
            nullptr, 0, 0, 1024, 512, 1024, 1024, 1024, 2048, 1048576, 524288, 2097152);
        tranb_k<<<gTf, tblk, 0, stream>>>(tcat, tt, 2048, 1024, 2097152, 524288);
        // T2 = 2 Lhat T1 - T0
        gemm_bt<6, 64><<<gL, 256, 0, stream>>>(abf, tt, nullptr, tcat + 512, nullptr, 0, nullptr,
            T0, 512, 524288, 1024, 512, 1024, 1024, 1024, 2048, 1048576, 524288, 2097152);
        tranb_k<<<gTf, tblk, 0, stream>>>(tcat + 512, tt, 2048, 1024, 2097152, 524288);
        // T3 = 2 Lhat T2 - T1
        gemm_bt<6, 64><<<gL, 256, 0, stream>>>(abf, tt, nullptr, tcat + 1024, nullptr, 0, nullptr,
            tcat, 2048, 2097152, 1024, 512, 1024, 1024, 1024, 2048, 1048576, 524288, 2097152);
        tranb_k<<<gTf, tblk, 0, stream>>>(tcat + 1024, tt, 2048, 1024, 2097152, 524288);
        // T4 = 2 Lhat T3 - T2
        gemm_bt<6, 64><<<gL, 256, 0, stream>>>(abf, tt, nullptr, tcat + 1536, nullptr, 0, nullptr,
            tcat + 512, 2048, 2097152, 1024, 512, 1024, 1024, 1024, 2048, 1048576, 524288, 2097152);
        // facc = T0 @ W0 ; out = relu(facc + Tcat @ Wcat + bias)
        gemm_bt<0, 64><<<dim3(Wn / 64, 64, 1), 256, 0, stream>>>(T0, W0, fa, nullptr, nullptr, 0,
            nullptr, nullptr, 0, 0, 8192, Wn, 512, 512, 512, Wn, 0, 0, 0);
        gemm_bt<2, 64><<<dim3(Wn / 64, 64, 1), 256, 0, stream>>>(tcat, Wcat, fa, outb, bias, 0,
            nullptr, nullptr, 0, 0, 8192, Wn, 2048, 2048, 2048, Wn, 0, 0, 0);
    };

    cheb(fea, wg1t0, wg1c, 512, bg1, x1, facc);
    cheb(x1,  wg2t0, wg2c, 384, bg2, x2, facc);

    // attention gate net + fused pooling tail
    gemm_bt<3, 64><<<dim3(2, 64, 1), 256, 0, stream>>>(x2, wp1t, nullptr, g1, bp1, 0, nullptr,
        nullptr, 0, 0, 8192, 128, 384, 384, 384, 128, 0, 0, 0);
    gemm_bt<3, 64><<<dim3(1, 64, 1), 256, 0, stream>>>(g1, wp2t, nullptr, g2, bp2, 0, nullptr,
        nullptr, 0, 0, 8192, 64, 128, 128, 128, 64, 0, 0, 0);
    pool_fused_k<<<8, 512, 0, stream>>>(g2, Wp3, bp3, maskv, x2, Wm1, bm1, Wm2, bm2, (float*)d_out);
}

// Round 7
// 783.888 us; speedup vs baseline: 1.1353x; 1.1353x over previous
//
#include <hip/hip_runtime.h>
#include <hip/hip_bf16.h>

typedef unsigned short u16;
typedef unsigned long long u64;
typedef float f32x4 __attribute__((ext_vector_type(4)));
typedef short s16x8 __attribute__((ext_vector_type(8)));

__device__ __forceinline__ float b2f(u16 u) {
    unsigned int x = ((unsigned int)u) << 16;
    return __builtin_bit_cast(float, x);
}
__device__ __forceinline__ u16 f2b(float f) {
    unsigned int x = __builtin_bit_cast(unsigned int, f);
    unsigned int lsb = (x >> 16) & 1u;
    x += 0x7fffu + lsb;                 // RNE; inputs are finite
    return (u16)(x >> 16);
}

#define GLOAD_LDS(g, l) __builtin_amdgcn_global_load_lds( \
    (const __attribute__((address_space(1))) void*)(g),   \
    (__attribute__((address_space(3))) void*)(l), 16, 0, 0)

// ---------------------------------------------------------------------------
// Batched GEMM: C[z,m,n] = sum_k A[z,m,k] * B[z,n,k]   (B stored [N][K])
// Tile 128xTN, BK=32, 256 threads = 4 waves, mfma_f32_16x16x32_bf16.
// Depth-2 pipeline: 3 LDS buffers, counted s_waitcnt vmcnt + raw s_barrier.
// Swapped-operand MFMA: acc[i][j][r] = C[m = wm+i*16+l15][n = wn+j*16+lg*4+r]
// so reg index r runs along columns -> packed 8B stores.
// EPI: 0 Cf=acc                      2 Cb=relu(acc+Cf+bias)
//      3 Cb=relu(acc+bias)*mask      4 Cb=acc*mask[row]*mask[col]
//      5 Cb=acc                      6 Cb=2*acc - prev2
// ---------------------------------------------------------------------------
template<int EPI, int TN>
__global__ __launch_bounds__(256)
void gemm_bt(const u16* __restrict__ A, const u16* __restrict__ B,
             float* __restrict__ Cf, u16* __restrict__ Cb,
             const float* __restrict__ bias, int biasBStride,
             const float* __restrict__ mask,
             const u16* __restrict__ prev2, int ldp, long pBS,
             int M, int N, int K, int lda, int ldb, int ldc,
             long aBS, long bBS, long cBS)
{
    constexpr int NJ = (TN == 128) ? 4 : 2;
    __shared__ u16 As[3][128 * 32];
    __shared__ u16 Bs[3][TN * 32];
    const int tid  = threadIdx.x;
    const int lane = tid & 63;
    const int z    = blockIdx.z;
    const int m0   = blockIdx.y * 128;
    const int n0   = blockIdx.x * TN;
    const int wm   = ((tid >> 7) & 1) * 64;
    const int wn   = ((tid >> 6) & 1) * (TN / 2);
    const int l15  = lane & 15;
    const int lg   = lane >> 4;
    const u16* Ab = A + (long)z * aBS;
    const u16* Bb = B + (long)z * bBS;

    f32x4 acc[4][NJ] = {};
    const int nt = K >> 5;

    auto stage = [&](int s, int t) {
        const int u0 = tid, u1 = tid + 256;
        GLOAD_LDS(Ab + (long)(m0 + (u0 >> 2)) * lda + t * 32 + (u0 & 3) * 8, &As[s][u0 * 8]);
        GLOAD_LDS(Ab + (long)(m0 + (u1 >> 2)) * lda + t * 32 + (u1 & 3) * 8, &As[s][u1 * 8]);
        GLOAD_LDS(Bb + (long)(n0 + (u0 >> 2)) * ldb + t * 32 + (u0 & 3) * 8, &Bs[s][u0 * 8]);
        if (TN == 128)
            GLOAD_LDS(Bb + (long)(n0 + (u1 >> 2)) * ldb + t * 32 + (u1 & 3) * 8, &Bs[s][u1 * 8]);
    };

    stage(0, 0);
    if (nt > 1) stage(1, 1);
    int cur = 0;
    for (int t = 0; t < nt; ++t) {
        if (t + 1 < nt) {
            if (TN == 128) asm volatile("s_waitcnt vmcnt(4) lgkmcnt(0)" ::: "memory");
            else           asm volatile("s_waitcnt vmcnt(3) lgkmcnt(0)" ::: "memory");
        } else {
            asm volatile("s_waitcnt vmcnt(0) lgkmcnt(0)" ::: "memory");
        }
        __builtin_amdgcn_s_barrier();
        s16x8 af[4], bg[NJ];
        #pragma unroll
        for (int i = 0; i < 4; ++i)
            af[i] = *(const s16x8*)&As[cur][(wm + i * 16 + l15) * 32 + lg * 8];
        #pragma unroll
        for (int j = 0; j < NJ; ++j)
            bg[j] = *(const s16x8*)&Bs[cur][(wn + j * 16 + l15) * 32 + lg * 8];
        if (t + 2 < nt) stage(cur == 0 ? 2 : cur - 1, t + 2);  // (cur+2)%3
        #pragma unroll
        for (int i = 0; i < 4; ++i)
            #pragma unroll
            for (int j = 0; j < NJ; ++j)
                acc[i][j] = __builtin_amdgcn_mfma_f32_16x16x32_bf16(bg[j], af[i], acc[i][j], 0, 0, 0);
        cur = (cur == 2) ? 0 : cur + 1;
    }

    const long cb0 = (long)z * cBS;
    #pragma unroll
    for (int i = 0; i < 4; ++i) {
        const int row = m0 + wm + i * 16 + l15;
        float rm = 1.f;
        if ((EPI == 3 || EPI == 4) && mask) rm = mask[z * M + row];
        #pragma unroll
        for (int j = 0; j < NJ; ++j) {
            const int nb = n0 + wn + j * 16 + lg * 4;
            if (nb >= N) continue;
            const long idx = cb0 + (long)row * ldc + nb;
            if (EPI == 0) {
                *(float4*)&Cf[idx] = make_float4(acc[i][j][0], acc[i][j][1], acc[i][j][2], acc[i][j][3]);
            } else {
                float x[4];
                if (EPI == 2) {
                    const float4 cv = *(const float4*)&Cf[idx];
                    x[0] = fmaxf(acc[i][j][0] + cv.x + bias[nb + 0], 0.f);
                    x[1] = fmaxf(acc[i][j][1] + cv.y + bias[nb + 1], 0.f);
                    x[2] = fmaxf(acc[i][j][2] + cv.z + bias[nb + 2], 0.f);
                    x[3] = fmaxf(acc[i][j][3] + cv.w + bias[nb + 3], 0.f);
                } else if (EPI == 3) {
                    const int bb0 = biasBStride ? ((z * M + row) >> 10) * biasBStride : 0;
                    #pragma unroll
                    for (int r = 0; r < 4; ++r) {
                        float v = fmaxf(acc[i][j][r] + bias[bb0 + nb + r], 0.f);
                        x[r] = mask ? v * rm : v;
                    }
                } else if (EPI == 4) {
                    #pragma unroll
                    for (int r = 0; r < 4; ++r)
                        x[r] = acc[i][j][r] * rm * mask[z * N + nb + r];
                } else if (EPI == 5) {
                    #pragma unroll
                    for (int r = 0; r < 4; ++r) x[r] = acc[i][j][r];
                } else {
                    const u64 pv = *(const u64*)&prev2[(long)z * pBS + (long)row * ldp + nb];
                    #pragma unroll
                    for (int r = 0; r < 4; ++r)
                        x[r] = 2.f * acc[i][j][r] - b2f((u16)(pv >> (16 * r)));
                }
                u64 pk = (u64)f2b(x[0]) | ((u64)f2b(x[1]) << 16)
                       | ((u64)f2b(x[2]) << 32) | ((u64)f2b(x[3]) << 48);
                *(u64*)&Cb[idx] = pk;
            }
        }
    }
}

// fp32 [K][N] -> bf16 [n][ldD] transpose+convert, zero pad for k in [K,Kpad)
__global__ void cvtT_k(const float* __restrict__ src, u16* __restrict__ dst,
                       int K, int N, int Kpad, int ldD, long sBS, long dBS)
{
    __shared__ float t[32][33];
    const int tx = threadIdx.x, ty = threadIdx.y;
    const int k0 = blockIdx.x * 32, n0 = blockIdx.y * 32;
    src += (long)blockIdx.z * sBS;
    dst += (long)blockIdx.z * dBS;
    #pragma unroll
    for (int rr = ty; rr < 32; rr += 8) {
        int k = k0 + rr, n = n0 + tx;
        t[rr][tx] = (k < K && n < N) ? src[(long)k * N + n] : 0.f;
    }
    __syncthreads();
    #pragma unroll
    for (int rr = ty; rr < 32; rr += 8) {
        int n = n0 + rr, k = k0 + tx;
        if (n < N && k < Kpad) dst[(long)n * ldD + k] = f2b(t[tx][rr]);
    }
}

// bf16 [R][C] (row stride lds_) -> bf16 [C][R] (row stride ldd_), batched
__global__ void tranb_k(const u16* __restrict__ src, u16* __restrict__ dst,
                        int lds_, int ldd_, long sBS, long dBS)
{
    __shared__ u16 t[32][33];
    const int tx = threadIdx.x, ty = threadIdx.y;
    const int r0 = blockIdx.y * 32, c0 = blockIdx.x * 32;
    src += (long)blockIdx.z * sBS;
    dst += (long)blockIdx.z * dBS;
    #pragma unroll
    for (int rr = ty; rr < 32; rr += 8)
        t[rr][tx] = src[(long)(r0 + rr) * lds_ + c0 + tx];
    __syncthreads();
    #pragma unroll
    for (int rr = ty; rr < 32; rr += 8)
        dst[(long)(c0 + rr) * ldd_ + r0 + tx] = t[tx][rr];
}

__global__ void cvt_k(const float* __restrict__ src, u16* __restrict__ dst, int n)
{
    for (long i = (long)(blockIdx.x * 256 + threadIdx.x) * 4; i < n; i += (long)gridDim.x * 1024) {
        float4 v = *(const float4*)&src[i];
        u64 pk = (u64)f2b(v.x) | ((u64)f2b(v.y) << 16)
               | ((u64)f2b(v.z) << 32) | ((u64)f2b(v.w) << 48);
        *(u64*)&dst[i] = pk;
    }
}

__global__ void zero_k(float* __restrict__ p, int n)
{
    const int i = blockIdx.x * 256 + threadIdx.x;
    if (i < n) p[i] = 0.f;
}

__global__ void mask_k(const float* __restrict__ inp, float* __restrict__ mask)
{
    const int row = blockIdx.x, tid = threadIdx.x;
    float4 v = *(const float4*)&inp[(long)row * 1024 + tid * 4];
    float s = v.x + v.y + v.z + v.w;
    __shared__ float red[256];
    red[tid] = s; __syncthreads();
    for (int o = 128; o > 0; o >>= 1) { if (tid < o) red[tid] += red[tid + o]; __syncthreads(); }
    if (tid == 0) mask[row] = (red[0] != 0.f) ? 1.f : 0.f;
}

// partial column sums of fea into mean (pre-zeroed), 64 blocks
__global__ void colmean_k(const u16* __restrict__ fea, float* __restrict__ mean)
{
    const int b = blockIdx.y, ch = blockIdx.x, f = threadIdx.x;   // 512
    const u16* p = fea + (long)b * 1024 * 512 + (long)ch * 128 * 512 + f;
    float s = 0.f;
    #pragma unroll 4
    for (int n = 0; n < 128; ++n) s += b2f(p[n * 512]);
    atomicAdd(&mean[b * 512 + f], s);
}

// fused: numel + c = relu(colsum/numel @ Wc + bc) + cb = ba1 + c@Wa1[512:]
// grid 8 (one block per batch), 512 threads; colsum precomputed in mean[]
__global__ void cvec_cb_k(const float* __restrict__ mean, const float* __restrict__ mask,
                          const float* __restrict__ Wc, const float* __restrict__ bc,
                          const float* __restrict__ Wa1, const float* __restrict__ ba1,
                          float* __restrict__ cb)
{
    const int b = blockIdx.x, tid = threadIdx.x;
    __shared__ float red[512];
    __shared__ float mn[512];
    __shared__ float cC[128];
    red[tid] = mask[b * 1024 + tid] + mask[b * 1024 + 512 + tid];
    __syncthreads();
    for (int o = 256; o > 0; o >>= 1) { if (tid < o) red[tid] += red[tid + o]; __syncthreads(); }
    const float numel = red[0];
    __syncthreads();
    mn[tid] = mean[b * 512 + tid] / numel;
    __syncthreads();
    const int o = tid & 127, q = tid >> 7;
    float cs = 0.f;
    for (int f = q * 128; f < q * 128 + 128; ++f) cs += mn[f] * Wc[f * 128 + o];
    red[tid] = cs;
    __syncthreads();
    if (tid < 256) red[tid] += red[tid + 256];
    __syncthreads();
    if (tid < 128) cC[tid] = fmaxf(red[tid] + red[tid + 128] + bc[tid], 0.f);
    __syncthreads();
    float t = ba1[tid];
    for (int jj = 0; jj < 128; ++jj) t += cC[jj] * Wa1[(512 + jj) * 512 + tid];
    cb[b * 512 + tid] = t;
}

__global__ void dinv_k(const u16* __restrict__ Abf, float* __restrict__ dinv)
{
    const int row = blockIdx.x, tid = threadIdx.x;
    const u16* p = Abf + (long)row * 1024 + tid * 4;
    float s = b2f(p[0]) + b2f(p[1]) + b2f(p[2]) + b2f(p[3]);
    __shared__ float red[256];
    red[tid] = s; __syncthreads();
    for (int o = 128; o > 0; o >>= 1) { if (tid < o) red[tid] += red[tid + o]; __syncthreads(); }
    if (tid == 0) {
        float d = red[0];
        dinv[row] = d > 0.f ? rsqrtf(fmaxf(d, 1e-30f)) : 0.f;
    }
}

__global__ void lhat_k(u16* __restrict__ Abf, const float* __restrict__ dinv)
{
    const long e0 = ((long)blockIdx.x * 256 + threadIdx.x) * 4;
    const int b = (int)(e0 >> 20);
    const int i = (int)((e0 >> 10) & 1023);
    const int j = (int)(e0 & 1023);
    const float di = dinv[b * 1024 + i];
    u16* p = Abf + e0;
    #pragma unroll
    for (int t = 0; t < 4; ++t) {
        float v = -di * b2f(p[t]) * dinv[b * 1024 + j + t];
        p[t] = f2b(v);
    }
}

__global__ void gate_k(const u16* __restrict__ g2, const float* __restrict__ Wp3,
                       const float* __restrict__ bp3, const float* __restrict__ mask,
                       float* __restrict__ gate)
{
    const int row = blockIdx.x * 4 + (threadIdx.x >> 6);
    const int lane = threadIdx.x & 63;
    float v = b2f(g2[row * 64 + lane]) * Wp3[lane];
    for (int o = 32; o > 0; o >>= 1) v += __shfl_xor(v, o, 64);
    if (lane == 0)
        gate[row] = (mask[row] > 0.f) ? tanhf(v + bp3[0]) : -1e9f;
}

// per-batch softmax over 1024 gates -> att
__global__ void attw_k(const float* __restrict__ gate, float* __restrict__ att)
{
    const int b = blockIdx.x, tid = threadIdx.x;  // 256
    const float* g = gate + b * 1024;
    float4 v = *(const float4*)&g[tid * 4];
    __shared__ float red[256];
    red[tid] = fmaxf(fmaxf(v.x, v.y), fmaxf(v.z, v.w));
    __syncthreads();
    for (int o = 128; o > 0; o >>= 1) { if (tid < o) red[tid] = fmaxf(red[tid], red[tid + o]); __syncthreads(); }
    const float mx = red[0];
    __syncthreads();
    float e0 = expf(v.x - mx), e1 = expf(v.y - mx), e2 = expf(v.z - mx), e3 = expf(v.w - mx);
    red[tid] = e0 + e1 + e2 + e3;
    __syncthreads();
    for (int o = 128; o > 0; o >>= 1) { if (tid < o) red[tid] += red[tid + o]; __syncthreads(); }
    const float zi = 1.f / red[0];
    float4 w = { e0 * zi, e1 * zi, e2 * zi, e3 * zi };
    *(float4*)&att[b * 1024 + tid * 4] = w;
}

// partial weighted sums into pooled (pre-zeroed), 64 blocks
__global__ void wsum_k(const float* __restrict__ att, const u16* __restrict__ x2,
                       float* __restrict__ pooled)
{
    const int b = blockIdx.y, ch = blockIdx.x, o = threadIdx.x;  // 384
    const u16* xb = x2 + (long)b * 1024 * 384 + (long)ch * 128 * 384 + o;
    const float* ab = att + b * 1024 + ch * 128;
    float s = 0.f;
    #pragma unroll 4
    for (int n = 0; n < 128; ++n) s += ab[n] * b2f(xb[n * 384]);
    atomicAdd(&pooled[b * 384 + o], s);
}

// output MLP, one block per batch
__global__ void final8_k(const float* __restrict__ pooled, const float* __restrict__ Wm1,
                         const float* __restrict__ bm1, const float* __restrict__ Wm2,
                         const float* __restrict__ bm2, float* __restrict__ out)
{
    __shared__ float pl[384];
    __shared__ float wred[4];
    const int b = blockIdx.x, tid = threadIdx.x;  // 256
    if (tid < 192) {
        pl[tid] = pooled[b * 384 + tid];
        pl[tid + 192] = pooled[b * 384 + tid + 192];
    }
    __syncthreads();
    float s = bm1[tid];
    for (int f = 0; f < 384; ++f) s += pl[f] * Wm1[f * 256 + tid];
    float h = fmaxf(s, 0.f) * Wm2[tid];
    for (int off = 32; off > 0; off >>= 1) h += __shfl_xor(h, off, 64);
    if ((tid & 63) == 0) wred[tid >> 6] = h;
    __syncthreads();
    if (tid == 0)
        out[b] = 1.f / (1.f + expf(-(wred[0] + wred[1] + wred[2] + wred[3] + bm2[0])));
}

// ---------------------------------------------------------------------------
// workspace layout
// ---------------------------------------------------------------------------
constexpr size_t OFS_WF1T = 0;                               // 832x1024 bf16
constexpr size_t OFS_WF2T = OFS_WF1T + 832ull * 1024 * 2;    // 512x800
constexpr size_t OFS_WF3T = OFS_WF2T + 512ull * 800 * 2;     // 512x512
constexpr size_t OFS_WA1T = OFS_WF3T + 512ull * 512 * 2;
constexpr size_t OFS_WA2T = OFS_WA1T + 512ull * 512 * 2;     // 384x512
constexpr size_t OFS_WG1T0 = OFS_WA2T + 384ull * 512 * 2;    // 512x512
constexpr size_t OFS_WG1C  = OFS_WG1T0 + 512ull * 512 * 2;   // 512x2048
constexpr size_t OFS_WG2T0 = OFS_WG1C + 512ull * 2048 * 2;   // 384x512
constexpr size_t OFS_WG2C  = OFS_WG2T0 + 384ull * 512 * 2;   // 384x2048
constexpr size_t OFS_WP1T  = OFS_WG2C + 384ull * 2048 * 2;   // 128x384
constexpr size_t OFS_WP2T  = OFS_WP1T + 128ull * 384 * 2;    // 64x128
constexpr size_t OFS_MASK  = OFS_WP2T + 64ull * 128 * 2;
constexpr size_t OFS_MEAN  = OFS_MASK + 32768;
constexpr size_t OFS_CB    = OFS_MEAN + 16384;
constexpr size_t OFS_DINV  = OFS_CB + 16384;
constexpr size_t OFS_GATE  = OFS_DINV + 32768;
constexpr size_t OFS_ATT   = OFS_GATE + 32768;
constexpr size_t OFS_POOL  = OFS_ATT + 32768;
constexpr size_t OFS_RA    = OFS_POOL + 16384;               // 16 MiB: xbf | a1,a2 | facc
constexpr size_t OFS_RB    = OFS_RA + 16777216;              // 12.5 MiB: h1 | tt
constexpr size_t OFS_RC    = OFS_RB + 13107200;              // 8 MiB: h2 | x1 | g1,g2
constexpr size_t OFS_RD    = OFS_RC + 8388608;               // 8 MiB: fea | x2
constexpr size_t OFS_RE    = OFS_RD + 8388608;               // 16 MiB: abf (Lhat)
constexpr size_t OFS_RF    = OFS_RE + 16777216;              // 32 MiB: Tcat (T1..T4)
constexpr size_t WS_TOTAL  = OFS_RF + 33554432;              // ~100.9 MiB

extern "C" void kernel_launch(void* const* d_in, const int* in_sizes, int n_in,
                              void* d_out, int out_size, void* d_ws, size_t ws_size,
                              hipStream_t stream)
{
    const float* inp = (const float*)d_in[0];
    const float* Wf1 = (const float*)d_in[2];  const float* bf1 = (const float*)d_in[3];
    const float* Wf2 = (const float*)d_in[4];  const float* bf2 = (const float*)d_in[5];
    const float* Wf3 = (const float*)d_in[6];  const float* bf3 = (const float*)d_in[7];
    const float* Wc  = (const float*)d_in[8];  const float* bc  = (const float*)d_in[9];
    const float* Wa1 = (const float*)d_in[10]; const float* ba1 = (const float*)d_in[11];
    const float* Wa2 = (const float*)d_in[12]; const float* ba2 = (const float*)d_in[13];
    const float* Wg1 = (const float*)d_in[14]; const float* bg1 = (const float*)d_in[15];
    const float* Wg2 = (const float*)d_in[16]; const float* bg2 = (const float*)d_in[17];
    const float* Wp1 = (const float*)d_in[18]; const float* bp1 = (const float*)d_in[19];
    const float* Wp2 = (const float*)d_in[20]; const float* bp2 = (const float*)d_in[21];
    const float* Wp3 = (const float*)d_in[22]; const float* bp3 = (const float*)d_in[23];
    const float* Wm1 = (const float*)d_in[24]; const float* bm1 = (const float*)d_in[25];
    const float* Wm2 = (const float*)d_in[26]; const float* bm2 = (const float*)d_in[27];

    if (ws_size < WS_TOTAL) return;
    char* ws = (char*)d_ws;

    u16* wf1t  = (u16*)(ws + OFS_WF1T);
    u16* wf2t  = (u16*)(ws + OFS_WF2T);
    u16* wf3t  = (u16*)(ws + OFS_WF3T);
    u16* wa1t  = (u16*)(ws + OFS_WA1T);
    u16* wa2t  = (u16*)(ws + OFS_WA2T);
    u16* wg1t0 = (u16*)(ws + OFS_WG1T0);
    u16* wg1c  = (u16*)(ws + OFS_WG1C);
    u16* wg2t0 = (u16*)(ws + OFS_WG2T0);
    u16* wg2c  = (u16*)(ws + OFS_WG2C);
    u16* wp1t  = (u16*)(ws + OFS_WP1T);
    u16* wp2t  = (u16*)(ws + OFS_WP2T);
    float* maskv   = (float*)(ws + OFS_MASK);
    float* meanv   = (float*)(ws + OFS_MEAN);
    float* cbv     = (float*)(ws + OFS_CB);
    float* dinvv   = (float*)(ws + OFS_DINV);
    float* gatev   = (float*)(ws + OFS_GATE);
    float* attv    = (float*)(ws + OFS_ATT);
    float* pooledv = (float*)(ws + OFS_POOL);

    u16*   xbf  = (u16*)(ws + OFS_RA);
    u16*   a1b  = (u16*)(ws + OFS_RA);                 // after f1
    u16*   a2b  = (u16*)(ws + OFS_RA + 8388608);
    float* facc = (float*)(ws + OFS_RA);               // after adjm
    u16*   h1   = (u16*)(ws + OFS_RB);
    u16*   tt   = (u16*)(ws + OFS_RB);                 // after f2
    u16*   h2   = (u16*)(ws + OFS_RC);
    u16*   x1   = (u16*)(ws + OFS_RC);                 // after f3
    u16*   g1   = (u16*)(ws + OFS_RC);                 // after cheb2
    u16*   g2   = (u16*)(ws + OFS_RC + 2097152);
    u16*   fea  = (u16*)(ws + OFS_RD);
    u16*   x2   = (u16*)(ws + OFS_RD);                 // after cheb1
    u16*   abf  = (u16*)(ws + OFS_RE);
    u16*   tcat = (u16*)(ws + OFS_RF);                 // [8192][2048] = T1..T4

    const dim3 tblk(32, 8);

    // weights: fp32 [K][N] -> bf16 [N][ld] (B^T layout for gemm_bt)
    cvtT_k<<<dim3(32, 25, 1), tblk, 0, stream>>>(Wf1, wf1t, 1024, 784, 1024, 1024, 0, 0);
    cvtT_k<<<dim3(25, 16, 1), tblk, 0, stream>>>(Wf2, wf2t, 784, 512, 800, 800, 0, 0);
    cvtT_k<<<dim3(16, 16, 1), tblk, 0, stream>>>(Wf3, wf3t, 512, 512, 512, 512, 0, 0);
    cvtT_k<<<dim3(16, 16, 1), tblk, 0, stream>>>(Wa1, wa1t, 512, 512, 512, 512, 0, 0);
    cvtT_k<<<dim3(16, 12, 1), tblk, 0, stream>>>(Wa2, wa2t, 512, 384, 512, 512, 0, 0);
    cvtT_k<<<dim3(16, 16, 1), tblk, 0, stream>>>(Wg1, wg1t0, 512, 512, 512, 512, 0, 0);
    cvtT_k<<<dim3(16, 16, 4), tblk, 0, stream>>>(Wg1 + 262144, wg1c, 512, 512, 512, 2048, 262144, 512);
    cvtT_k<<<dim3(16, 12, 1), tblk, 0, stream>>>(Wg2, wg2t0, 512, 384, 512, 512, 0, 0);
    cvtT_k<<<dim3(16, 12, 4), tblk, 0, stream>>>(Wg2 + 196608, wg2c, 512, 384, 512, 2048, 196608, 512);
    cvtT_k<<<dim3(12, 4, 1),  tblk, 0, stream>>>(Wp1, wp1t, 384, 128, 384, 384, 0, 0);
    cvtT_k<<<dim3(4, 2, 1),   tblk, 0, stream>>>(Wp2, wp2t, 128, 64, 128, 128, 0, 0);

    cvt_k<<<4096, 256, 0, stream>>>(inp, xbf, 8 * 1024 * 1024);
    mask_k<<<8192, 256, 0, stream>>>(inp, maskv);

    // fe_extrator
    gemm_bt<3, 64><<<dim3(13, 64, 1), 256, 0, stream>>>(xbf, wf1t, nullptr, h1, bf1, 0, maskv,
        nullptr, 0, 0, 8192, 784, 1024, 1024, 1024, 800, 0, 0, 0);
    gemm_bt<3, 64><<<dim3(8, 64, 1), 256, 0, stream>>>(h1, wf2t, nullptr, h2, bf2, 0, maskv,
        nullptr, 0, 0, 8192, 512, 800, 800, 800, 512, 0, 0, 0);
    gemm_bt<3, 64><<<dim3(8, 64, 1), 256, 0, stream>>>(h2, wf3t, nullptr, fea, bf3, 0, maskv,
        nullptr, 0, 0, 8192, 512, 512, 512, 512, 512, 0, 0, 0);

    // c vector + per-batch bias for adj layer 1
    zero_k<<<16, 256, 0, stream>>>(meanv, 8 * 512);
    colmean_k<<<dim3(8, 8), 512, 0, stream>>>(fea, meanv);
    cvec_cb_k<<<8, 512, 0, stream>>>(meanv, maskv, Wc, bc, Wa1, ba1, cbv);

    // adj net
    gemm_bt<3, 64><<<dim3(8, 64, 1), 256, 0, stream>>>(fea, wa1t, nullptr, a1b, cbv, 512, maskv,
        nullptr, 0, 0, 8192, 512, 512, 512, 512, 512, 0, 0, 0);
    gemm_bt<3, 64><<<dim3(6, 64, 1), 256, 0, stream>>>(a1b, wa2t, nullptr, a2b, ba2, 0, maskv,
        nullptr, 0, 0, 8192, 384, 512, 512, 512, 384, 0, 0, 0);

    // adjacency, degree, Lhat (in place)
    gemm_bt<4, 64><<<dim3(16, 8, 8), 256, 0, stream>>>(a2b, a2b, nullptr, abf, nullptr, 0, maskv,
        nullptr, 0, 0, 1024, 1024, 384, 384, 384, 1024, 393216, 393216, 1048576);
    dinv_k<<<8192, 256, 0, stream>>>(abf, dinvv);
    lhat_k<<<8192, 256, 0, stream>>>(abf, dinvv);

    // ChebConv: T0 separate, T1..T4 K-concat in tcat; out = T0@W0 + Tcat@Wcat + b
    auto cheb = [&](const u16* T0, const u16* W0, const u16* Wcat, int Wn,
                    const float* bias, u16* outb, float* fa) {
        const dim3 gL(8, 8, 8);
        const dim3 gTf(16, 32, 8);
        // tt = T0^T
        tranb_k<<<gTf, tblk, 0, stream>>>(T0, tt, 512, 1024, 524288, 524288);
        // T1 = Lhat @ T0
        gemm_bt<5, 64><<<gL, 256, 0, stream>>>(abf, tt, nullptr, tcat, nullptr, 0, nullptr,
            nullptr, 0, 0, 1024, 512, 1024, 1024, 1024, 2048, 1048576, 524288, 2097152);
        tranb_k<<<gTf, tblk, 0, stream>>>(tcat, tt, 2048, 1024, 2097152, 524288);
        // T2 = 2 Lhat T1 - T0
        gemm_bt<6, 64><<<gL, 256, 0, stream>>>(abf, tt, nullptr, tcat + 512, nullptr, 0, nullptr,
            T0, 512, 524288, 1024, 512, 1024, 1024, 1024, 2048, 1048576, 524288, 2097152);
        tranb_k<<<gTf, tblk, 0, stream>>>(tcat + 512, tt, 2048, 1024, 2097152, 524288);
        // T3 = 2 Lhat T2 - T1
        gemm_bt<6, 64><<<gL, 256, 0, stream>>>(abf, tt, nullptr, tcat + 1024, nullptr, 0, nullptr,
            tcat, 2048, 2097152, 1024, 512, 1024, 1024, 1024, 2048, 1048576, 524288, 2097152);
        tranb_k<<<gTf, tblk, 0, stream>>>(tcat + 1024, tt, 2048, 1024, 2097152, 524288);
        // T4 = 2 Lhat T3 - T2
        gemm_bt<6, 64><<<gL, 256, 0, stream>>>(abf, tt, nullptr, tcat + 1536, nullptr, 0, nullptr,
            tcat + 512, 2048, 2097152, 1024, 512, 1024, 1024, 1024, 2048, 1048576, 524288, 2097152);
        // facc = T0 @ W0 ; out = relu(facc + Tcat @ Wcat + bias)
        gemm_bt<0, 64><<<dim3(Wn / 64, 64, 1), 256, 0, stream>>>(T0, W0, fa, nullptr, nullptr, 0,
            nullptr, nullptr, 0, 0, 8192, Wn, 512, 512, 512, Wn, 0, 0, 0);
        gemm_bt<2, 64><<<dim3(Wn / 64, 64, 1), 256, 0, stream>>>(tcat, Wcat, fa, outb, bias, 0,
            nullptr, nullptr, 0, 0, 8192, Wn, 2048, 2048, 2048, Wn, 0, 0, 0);
    };

    cheb(fea, wg1t0, wg1c, 512, bg1, x1, facc);
    cheb(x1,  wg2t0, wg2c, 384, bg2, x2, facc);

    // attention gate net + pooling tail
    gemm_bt<3, 64><<<dim3(2, 64, 1), 256, 0, stream>>>(x2, wp1t, nullptr, g1, bp1, 0, nullptr,
        nullptr, 0, 0, 8192, 128, 384, 384, 384, 128, 0, 0, 0);
    gemm_bt<3, 64><<<dim3(1, 64, 1), 256, 0, stream>>>(g1, wp2t, nullptr, g2, bp2, 0, nullptr,
        nullptr, 0, 0, 8192, 64, 128, 128, 128, 64, 0, 0, 0);
    gate_k<<<2048, 256, 0, stream>>>(g2, Wp3, bp3, maskv, gatev);
    attw_k<<<8, 256, 0, stream>>>(gatev, attv);
    zero_k<<<12, 256, 0, stream>>>(pooledv, 8 * 384);
    wsum_k<<<dim3(8, 8), 384, 0, stream>>>(attv, x2, pooledv);
    final8_k<<<8, 256, 0, stream>>>(pooledv, Wm1, bm1, Wm2, bm2, (float*)d_out);
}

// Round 8
// 705.771 us; speedup vs baseline: 1.2610x; 1.1107x over previous
//
#include <hip/hip_runtime.h>
#include <hip/hip_bf16.h>

typedef unsigned short u16;
typedef unsigned long long u64;
typedef float f32x4 __attribute__((ext_vector_type(4)));
typedef short s16x8 __attribute__((ext_vector_type(8)));

__device__ __forceinline__ float b2f(u16 u) {
    unsigned int x = ((unsigned int)u) << 16;
    return __builtin_bit_cast(float, x);
}
__device__ __forceinline__ u16 f2b(float f) {
    unsigned int x = __builtin_bit_cast(unsigned int, f);
    unsigned int lsb = (x >> 16) & 1u;
    x += 0x7fffu + lsb;                 // RNE; inputs are finite
    return (u16)(x >> 16);
}

#define GLOAD_LDS(g, l) __builtin_amdgcn_global_load_lds( \
    (const __attribute__((address_space(1))) void*)(g),   \
    (__attribute__((address_space(3))) void*)(l), 16, 0, 0)

// ---------------------------------------------------------------------------
// Batched GEMM: C[z,m,n] = sum_k A[z,m,k] * B[z,n,k]   (B stored [N][K])
// Tile 128xTN, BK=32, 256 threads = 4 waves, mfma_f32_16x16x32_bf16.
// Depth-2 pipeline: 3 LDS buffers, counted s_waitcnt vmcnt + raw s_barrier.
// Swapped-operand MFMA: acc[i][j][r] = C[m = wm+i*16+l15][n = wn+j*16+lg*4+r]
// so reg index r runs along columns -> packed 8B stores.
// EPI: 0 Cf=acc                      2 Cb=relu(acc+Cf+bias)
//      3 Cb=relu(acc+bias)*mask      4 Cb=acc*mask[row]*mask[col]
//      5 Cb=acc                      6 Cb=2*acc - prev2
// ---------------------------------------------------------------------------
template<int EPI, int TN>
__global__ __launch_bounds__(256)
void gemm_bt(const u16* __restrict__ A, const u16* __restrict__ B,
             float* __restrict__ Cf, u16* __restrict__ Cb,
             const float* __restrict__ bias, int biasBStride,
             const float* __restrict__ mask,
             const u16* __restrict__ prev2, int ldp, long pBS,
             int M, int N, int K, int lda, int ldb, int ldc,
             long aBS, long bBS, long cBS)
{
    constexpr int NJ = (TN == 128) ? 4 : 2;
    __shared__ u16 As[3][128 * 32];
    __shared__ u16 Bs[3][TN * 32];
    const int tid  = threadIdx.x;
    const int lane = tid & 63;
    const int z    = blockIdx.z;
    const int m0   = blockIdx.y * 128;
    const int n0   = blockIdx.x * TN;
    const int wm   = ((tid >> 7) & 1) * 64;
    const int wn   = ((tid >> 6) & 1) * (TN / 2);
    const int l15  = lane & 15;
    const int lg   = lane >> 4;
    const u16* Ab = A + (long)z * aBS;
    const u16* Bb = B + (long)z * bBS;

    f32x4 acc[4][NJ] = {};
    const int nt = K >> 5;

    auto stage = [&](int s, int t) {
        const int u0 = tid, u1 = tid + 256;
        GLOAD_LDS(Ab + (long)(m0 + (u0 >> 2)) * lda + t * 32 + (u0 & 3) * 8, &As[s][u0 * 8]);
        GLOAD_LDS(Ab + (long)(m0 + (u1 >> 2)) * lda + t * 32 + (u1 & 3) * 8, &As[s][u1 * 8]);
        GLOAD_LDS(Bb + (long)(n0 + (u0 >> 2)) * ldb + t * 32 + (u0 & 3) * 8, &Bs[s][u0 * 8]);
        if (TN == 128)
            GLOAD_LDS(Bb + (long)(n0 + (u1 >> 2)) * ldb + t * 32 + (u1 & 3) * 8, &Bs[s][u1 * 8]);
    };

    stage(0, 0);
    if (nt > 1) stage(1, 1);
    int cur = 0;
    for (int t = 0; t < nt; ++t) {
        if (t + 1 < nt) {
            if (TN == 128) asm volatile("s_waitcnt vmcnt(4) lgkmcnt(0)" ::: "memory");
            else           asm volatile("s_waitcnt vmcnt(3) lgkmcnt(0)" ::: "memory");
        } else {
            asm volatile("s_waitcnt vmcnt(0) lgkmcnt(0)" ::: "memory");
        }
        __builtin_amdgcn_s_barrier();
        s16x8 af[4], bg[NJ];
        #pragma unroll
        for (int i = 0; i < 4; ++i)
            af[i] = *(const s16x8*)&As[cur][(wm + i * 16 + l15) * 32 + lg * 8];
        #pragma unroll
        for (int j = 0; j < NJ; ++j)
            bg[j] = *(const s16x8*)&Bs[cur][(wn + j * 16 + l15) * 32 + lg * 8];
        if (t + 2 < nt) stage(cur == 0 ? 2 : cur - 1, t + 2);  // (cur+2)%3
        #pragma unroll
        for (int i = 0; i < 4; ++i)
            #pragma unroll
            for (int j = 0; j < NJ; ++j)
                acc[i][j] = __builtin_amdgcn_mfma_f32_16x16x32_bf16(bg[j], af[i], acc[i][j], 0, 0, 0);
        cur = (cur == 2) ? 0 : cur + 1;
    }

    const long cb0 = (long)z * cBS;
    #pragma unroll
    for (int i = 0; i < 4; ++i) {
        const int row = m0 + wm + i * 16 + l15;
        float rm = 1.f;
        if ((EPI == 3 || EPI == 4) && mask) rm = mask[z * M + row];
        #pragma unroll
        for (int j = 0; j < NJ; ++j) {
            const int nb = n0 + wn + j * 16 + lg * 4;
            if (nb >= N) continue;
            const long idx = cb0 + (long)row * ldc + nb;
            if (EPI == 0) {
                *(float4*)&Cf[idx] = make_float4(acc[i][j][0], acc[i][j][1], acc[i][j][2], acc[i][j][3]);
            } else {
                float x[4];
                if (EPI == 2) {
                    const float4 cv = *(const float4*)&Cf[idx];
                    x[0] = fmaxf(acc[i][j][0] + cv.x + bias[nb + 0], 0.f);
                    x[1] = fmaxf(acc[i][j][1] + cv.y + bias[nb + 1], 0.f);
                    x[2] = fmaxf(acc[i][j][2] + cv.z + bias[nb + 2], 0.f);
                    x[3] = fmaxf(acc[i][j][3] + cv.w + bias[nb + 3], 0.f);
                } else if (EPI == 3) {
                    const int bb0 = biasBStride ? ((z * M + row) >> 10) * biasBStride : 0;
                    #pragma unroll
                    for (int r = 0; r < 4; ++r) {
                        float v = fmaxf(acc[i][j][r] + bias[bb0 + nb + r], 0.f);
                        x[r] = mask ? v * rm : v;
                    }
                } else if (EPI == 4) {
                    #pragma unroll
                    for (int r = 0; r < 4; ++r)
                        x[r] = acc[i][j][r] * rm * mask[z * N + nb + r];
                } else if (EPI == 5) {
                    #pragma unroll
                    for (int r = 0; r < 4; ++r) x[r] = acc[i][j][r];
                } else {
                    const u64 pv = *(const u64*)&prev2[(long)z * pBS + (long)row * ldp + nb];
                    #pragma unroll
                    for (int r = 0; r < 4; ++r)
                        x[r] = 2.f * acc[i][j][r] - b2f((u16)(pv >> (16 * r)));
                }
                u64 pk = (u64)f2b(x[0]) | ((u64)f2b(x[1]) << 16)
                       | ((u64)f2b(x[2]) << 32) | ((u64)f2b(x[3]) << 48);
                *(u64*)&Cb[idx] = pk;
            }
        }
    }
}

// ---------------------------------------------------------------------------
// all 11 weight conversions (fp32 [K][N] -> bf16 [n][ldD], zero-padded) in ONE
// dispatch: flat block id -> job lookup via cumulative block counts.
// ---------------------------------------------------------------------------
struct CvtJobs {
    const float* src[11];
    u16* dst[11];
    int K[11], N[11], Kpad[11], ldD[11];
    long sBS[11], dBS[11];
    int gx[11], gy[11];
    int cum[12];
};

__global__ void cvtT_all(CvtJobs J)
{
    __shared__ float t[32][33];
    const int bid = blockIdx.x;
    int j = 0;
    #pragma unroll
    for (int q = 0; q < 11; ++q) if (bid >= J.cum[q + 1]) j = q + 1;
    const int local = bid - J.cum[j];
    const int bx = local % J.gx[j];
    const int rem = local / J.gx[j];
    const int by = rem % J.gy[j];
    const int bz = rem / J.gy[j];
    const float* src = J.src[j] + (long)bz * J.sBS[j];
    u16* dst = J.dst[j] + (long)bz * J.dBS[j];
    const int K = J.K[j], N = J.N[j], Kpad = J.Kpad[j], ldD = J.ldD[j];
    const int tx = threadIdx.x, ty = threadIdx.y;
    const int k0 = bx * 32, n0 = by * 32;
    #pragma unroll
    for (int rr = ty; rr < 32; rr += 8) {
        int k = k0 + rr, n = n0 + tx;
        t[rr][tx] = (k < K && n < N) ? src[(long)k * N + n] : 0.f;
    }
    __syncthreads();
    #pragma unroll
    for (int rr = ty; rr < 32; rr += 8) {
        int n = n0 + rr, k = k0 + tx;
        if (n < N && k < Kpad) dst[(long)n * ldD + k] = f2b(t[tx][rr]);
    }
}

// bf16 [R][C] (row stride lds_) -> bf16 [C][R] (row stride ldd_), batched.
// 64x64 tiles, u64 (4xbf16) loads and stores; LDS pad 2 -> <=2-way conflicts.
__global__ __launch_bounds__(256)
void tranb64_k(const u16* __restrict__ src, u16* __restrict__ dst,
               int lds_, int ldd_, long sBS, long dBS)
{
    __shared__ u16 t[64][66];
    const int tid = threadIdx.x;
    const int r0 = blockIdx.y * 64, c0 = blockIdx.x * 64;
    src += (long)blockIdx.z * sBS;
    dst += (long)blockIdx.z * dBS;
    #pragma unroll
    for (int q = 0; q < 4; ++q) {
        const int lin = tid + q * 256;
        const int row = lin >> 4, c4 = (lin & 15) * 4;
        const u64 v = *(const u64*)&src[(long)(r0 + row) * lds_ + c0 + c4];
        t[row][c4 + 0] = (u16)(v);
        t[row][c4 + 1] = (u16)(v >> 16);
        t[row][c4 + 2] = (u16)(v >> 32);
        t[row][c4 + 3] = (u16)(v >> 48);
    }
    __syncthreads();
    #pragma unroll
    for (int q = 0; q < 4; ++q) {
        const int lin = tid + q * 256;
        const int col = lin >> 4, r4 = (lin & 15) * 4;
        u64 v = (u64)t[r4 + 0][col] | ((u64)t[r4 + 1][col] << 16)
              | ((u64)t[r4 + 2][col] << 32) | ((u64)t[r4 + 3][col] << 48);
        *(u64*)&dst[(long)(c0 + col) * ldd_ + r0 + r4] = v;
    }
}

// fused mask + fp32->bf16 convert: one block per node row
__global__ void maskcvt_k(const float* __restrict__ inp, u16* __restrict__ xbf,
                          float* __restrict__ mask)
{
    const int row = blockIdx.x, tid = threadIdx.x;
    const long base = (long)row * 1024 + tid * 4;
    float4 v = *(const float4*)&inp[base];
    u64 pk = (u64)f2b(v.x) | ((u64)f2b(v.y) << 16)
           | ((u64)f2b(v.z) << 32) | ((u64)f2b(v.w) << 48);
    *(u64*)&xbf[base] = pk;
    float s = v.x + v.y + v.z + v.w;
    __shared__ float red[256];
    red[tid] = s; __syncthreads();
    for (int o = 128; o > 0; o >>= 1) { if (tid < o) red[tid] += red[tid + o]; __syncthreads(); }
    if (tid == 0) mask[row] = (red[0] != 0.f) ? 1.f : 0.f;
}

__global__ void zero_k(float* __restrict__ p, int n)
{
    const int i = blockIdx.x * 256 + threadIdx.x;
    if (i < n) p[i] = 0.f;
}

// partial column sums of fea into mean (pre-zeroed), 64 blocks
__global__ void colmean_k(const u16* __restrict__ fea, float* __restrict__ mean)
{
    const int b = blockIdx.y, ch = blockIdx.x, f = threadIdx.x;   // 512
    const u16* p = fea + (long)b * 1024 * 512 + (long)ch * 128 * 512 + f;
    float s = 0.f;
    #pragma unroll 4
    for (int n = 0; n < 128; ++n) s += b2f(p[n * 512]);
    atomicAdd(&mean[b * 512 + f], s);
}

// c = relu((colsum/numel) @ Wc + bc), grid 8, 512 threads
__global__ void cvec8_k(const float* __restrict__ mean, const float* __restrict__ mask,
                        const float* __restrict__ Wc, const float* __restrict__ bc,
                        float* __restrict__ c)
{
    const int b = blockIdx.x, tid = threadIdx.x;
    __shared__ float red[512];
    __shared__ float mn[512];
    red[tid] = mask[b * 1024 + tid] + mask[b * 1024 + 512 + tid];
    __syncthreads();
    for (int o = 256; o > 0; o >>= 1) { if (tid < o) red[tid] += red[tid + o]; __syncthreads(); }
    const float numel = red[0];
    __syncthreads();
    mn[tid] = mean[b * 512 + tid] / numel;
    __syncthreads();
    const int o = tid & 127, q = tid >> 7;
    float cs = 0.f;
    #pragma unroll 8
    for (int f = q * 128; f < q * 128 + 128; ++f) cs += mn[f] * Wc[f * 128 + o];
    red[tid] = cs;
    __syncthreads();
    if (tid < 256) red[tid] += red[tid + 256];
    __syncthreads();
    if (tid < 128) c[b * 128 + tid] = fmaxf(red[tid] + red[tid + 128] + bc[tid], 0.f);
}

// cb[b][o] = ba1[o] + sum_j c[b][j]*Wa1[512+j][o]; grid (8 oc-chunks, 8 batch)
__global__ void cb64_k(const float* __restrict__ c, const float* __restrict__ Wa1,
                       const float* __restrict__ ba1, float* __restrict__ cb)
{
    const int oc = blockIdx.x, b = blockIdx.y, tid = threadIdx.x;  // 256
    __shared__ float cC[128];
    __shared__ float red[256];
    if (tid < 128) cC[tid] = c[b * 128 + tid];
    __syncthreads();
    const int o = tid & 63, part = tid >> 6;     // 4 partials per output
    const float* w = Wa1 + (long)(512 + part * 32) * 512 + oc * 64 + o;
    float s = 0.f;
    #pragma unroll 8
    for (int j = 0; j < 32; ++j) s += cC[part * 32 + j] * w[j * 512];
    red[tid] = s;
    __syncthreads();
    if (tid < 64) {
        float tot = red[tid] + red[tid + 64] + red[tid + 128] + red[tid + 192]
                  + ba1[oc * 64 + tid];
        cb[b * 512 + oc * 64 + tid] = tot;
    }
}

__global__ void dinv_k(const u16* __restrict__ Abf, float* __restrict__ dinv)
{
    const int row = blockIdx.x, tid = threadIdx.x;
    const u16* p = Abf + (long)row * 1024 + tid * 4;
    float s = b2f(p[0]) + b2f(p[1]) + b2f(p[2]) + b2f(p[3]);
    __shared__ float red[256];
    red[tid] = s; __syncthreads();
    for (int o = 128; o > 0; o >>= 1) { if (tid < o) red[tid] += red[tid + o]; __syncthreads(); }
    if (tid == 0) {
        float d = red[0];
        dinv[row] = d > 0.f ? rsqrtf(fmaxf(d, 1e-30f)) : 0.f;
    }
}

__global__ void lhat_k(u16* __restrict__ Abf, const float* __restrict__ dinv)
{
    const long e0 = ((long)blockIdx.x * 256 + threadIdx.x) * 4;
    const int b = (int)(e0 >> 20);
    const int i = (int)((e0 >> 10) & 1023);
    const int j = (int)(e0 & 1023);
    const float di = dinv[b * 1024 + i];
    u16* p = Abf + e0;
    #pragma unroll
    for (int t = 0; t < 4; ++t) {
        float v = -di * b2f(p[t]) * dinv[b * 1024 + j + t];
        p[t] = f2b(v);
    }
}

__global__ void gate_k(const u16* __restrict__ g2, const float* __restrict__ Wp3,
                       const float* __restrict__ bp3, const float* __restrict__ mask,
                       float* __restrict__ gate)
{
    const int row = blockIdx.x * 4 + (threadIdx.x >> 6);
    const int lane = threadIdx.x & 63;
    float v = b2f(g2[row * 64 + lane]) * Wp3[lane];
    for (int o = 32; o > 0; o >>= 1) v += __shfl_xor(v, o, 64);
    if (lane == 0)
        gate[row] = (mask[row] > 0.f) ? tanhf(v + bp3[0]) : -1e9f;
}

// per-batch softmax over 1024 gates -> att
__global__ void attw_k(const float* __restrict__ gate, float* __restrict__ att)
{
    const int b = blockIdx.x, tid = threadIdx.x;  // 256
    const float* g = gate + b * 1024;
    float4 v = *(const float4*)&g[tid * 4];
    __shared__ float red[256];
    red[tid] = fmaxf(fmaxf(v.x, v.y), fmaxf(v.z, v.w));
    __syncthreads();
    for (int o = 128; o > 0; o >>= 1) { if (tid < o) red[tid] = fmaxf(red[tid], red[tid + o]); __syncthreads(); }
    const float mx = red[0];
    __syncthreads();
    float e0 = expf(v.x - mx), e1 = expf(v.y - mx), e2 = expf(v.z - mx), e3 = expf(v.w - mx);
    red[tid] = e0 + e1 + e2 + e3;
    __syncthreads();
    for (int o = 128; o > 0; o >>= 1) { if (tid < o) red[tid] += red[tid + o]; __syncthreads(); }
    const float zi = 1.f / red[0];
    float4 w = { e0 * zi, e1 * zi, e2 * zi, e3 * zi };
    *(float4*)&att[b * 1024 + tid * 4] = w;
}

// partial weighted sums into pooled (pre-zeroed), 64 blocks
__global__ void wsum_k(const float* __restrict__ att, const u16* __restrict__ x2,
                       float* __restrict__ pooled)
{
    const int b = blockIdx.y, ch = blockIdx.x, o = threadIdx.x;  // 384
    const u16* xb = x2 + (long)b * 1024 * 384 + (long)ch * 128 * 384 + o;
    const float* ab = att + b * 1024 + ch * 128;
    float s = 0.f;
    #pragma unroll 4
    for (int n = 0; n < 128; ++n) s += ab[n] * b2f(xb[n * 384]);
    atomicAdd(&pooled[b * 384 + o], s);
}

// output MLP, one block per batch
__global__ void final8_k(const float* __restrict__ pooled, const float* __restrict__ Wm1,
                         const float* __restrict__ bm1, const float* __restrict__ Wm2,
                         const float* __restrict__ bm2, float* __restrict__ out)
{
    __shared__ float pl[384];
    __shared__ float wred[4];
    const int b = blockIdx.x, tid = threadIdx.x;  // 256
    if (tid < 192) {
        pl[tid] = pooled[b * 384 + tid];
        pl[tid + 192] = pooled[b * 384 + tid + 192];
    }
    __syncthreads();
    float s = bm1[tid];
    for (int f = 0; f < 384; ++f) s += pl[f] * Wm1[f * 256 + tid];
    float h = fmaxf(s, 0.f) * Wm2[tid];
    for (int off = 32; off > 0; off >>= 1) h += __shfl_xor(h, off, 64);
    if ((tid & 63) == 0) wred[tid >> 6] = h;
    __syncthreads();
    if (tid == 0)
        out[b] = 1.f / (1.f + expf(-(wred[0] + wred[1] + wred[2] + wred[3] + bm2[0])));
}

// ---------------------------------------------------------------------------
// workspace layout
// ---------------------------------------------------------------------------
constexpr size_t OFS_WF1T = 0;                               // 832x1024 bf16
constexpr size_t OFS_WF2T = OFS_WF1T + 832ull * 1024 * 2;    // 512x800
constexpr size_t OFS_WF3T = OFS_WF2T + 512ull * 800 * 2;     // 512x512
constexpr size_t OFS_WA1T = OFS_WF3T + 512ull * 512 * 2;
constexpr size_t OFS_WA2T = OFS_WA1T + 512ull * 512 * 2;     // 384x512
constexpr size_t OFS_WG1T0 = OFS_WA2T + 384ull * 512 * 2;    // 512x512
constexpr size_t OFS_WG1C  = OFS_WG1T0 + 512ull * 512 * 2;   // 512x2048
constexpr size_t OFS_WG2T0 = OFS_WG1C + 512ull * 2048 * 2;   // 384x512
constexpr size_t OFS_WG2C  = OFS_WG2T0 + 384ull * 512 * 2;   // 384x2048
constexpr size_t OFS_WP1T  = OFS_WG2C + 384ull * 2048 * 2;   // 128x384
constexpr size_t OFS_WP2T  = OFS_WP1T + 128ull * 384 * 2;    // 64x128
constexpr size_t OFS_MASK  = OFS_WP2T + 64ull * 128 * 2;
constexpr size_t OFS_MEAN  = OFS_MASK + 32768;
constexpr size_t OFS_CVEC  = OFS_MEAN + 16384;
constexpr size_t OFS_CB    = OFS_CVEC + 4096;
constexpr size_t OFS_DINV  = OFS_CB + 16384;
constexpr size_t OFS_GATE  = OFS_DINV + 32768;
constexpr size_t OFS_ATT   = OFS_GATE + 32768;
constexpr size_t OFS_POOL  = OFS_ATT + 32768;
constexpr size_t OFS_RA    = OFS_POOL + 16384;               // 16 MiB: xbf | a1,a2 | facc
constexpr size_t OFS_RB    = OFS_RA + 16777216;              // 12.5 MiB: h1 | tt
constexpr size_t OFS_RC    = OFS_RB + 13107200;              // 8 MiB: h2 | x1 | g1,g2
constexpr size_t OFS_RD    = OFS_RC + 8388608;               // 8 MiB: fea | x2
constexpr size_t OFS_RE    = OFS_RD + 8388608;               // 16 MiB: abf (Lhat)
constexpr size_t OFS_RF    = OFS_RE + 16777216;              // 32 MiB: Tcat (T1..T4)
constexpr size_t WS_TOTAL  = OFS_RF + 33554432;              // ~100.9 MiB

extern "C" void kernel_launch(void* const* d_in, const int* in_sizes, int n_in,
                              void* d_out, int out_size, void* d_ws, size_t ws_size,
                              hipStream_t stream)
{
    const float* inp = (const float*)d_in[0];
    const float* Wf1 = (const float*)d_in[2];  const float* bf1 = (const float*)d_in[3];
    const float* Wf2 = (const float*)d_in[4];  const float* bf2 = (const float*)d_in[5];
    const float* Wf3 = (const float*)d_in[6];  const float* bf3 = (const float*)d_in[7];
    const float* Wc  = (const float*)d_in[8];  const float* bc  = (const float*)d_in[9];
    const float* Wa1 = (const float*)d_in[10]; const float* ba1 = (const float*)d_in[11];
    const float* Wa2 = (const float*)d_in[12]; const float* ba2 = (const float*)d_in[13];
    const float* Wg1 = (const float*)d_in[14]; const float* bg1 = (const float*)d_in[15];
    const float* Wg2 = (const float*)d_in[16]; const float* bg2 = (const float*)d_in[17];
    const float* Wp1 = (const float*)d_in[18]; const float* bp1 = (const float*)d_in[19];
    const float* Wp2 = (const float*)d_in[20]; const float* bp2 = (const float*)d_in[21];
    const float* Wp3 = (const float*)d_in[22]; const float* bp3 = (const float*)d_in[23];
    const float* Wm1 = (const float*)d_in[24]; const float* bm1 = (const float*)d_in[25];
    const float* Wm2 = (const float*)d_in[26]; const float* bm2 = (const float*)d_in[27];

    if (ws_size < WS_TOTAL) return;
    char* ws = (char*)d_ws;

    u16* wf1t  = (u16*)(ws + OFS_WF1T);
    u16* wf2t  = (u16*)(ws + OFS_WF2T);
    u16* wf3t  = (u16*)(ws + OFS_WF3T);
    u16* wa1t  = (u16*)(ws + OFS_WA1T);
    u16* wa2t  = (u16*)(ws + OFS_WA2T);
    u16* wg1t0 = (u16*)(ws + OFS_WG1T0);
    u16* wg1c  = (u16*)(ws + OFS_WG1C);
    u16* wg2t0 = (u16*)(ws + OFS_WG2T0);
    u16* wg2c  = (u16*)(ws + OFS_WG2C);
    u16* wp1t  = (u16*)(ws + OFS_WP1T);
    u16* wp2t  = (u16*)(ws + OFS_WP2T);
    float* maskv   = (float*)(ws + OFS_MASK);
    float* meanv   = (float*)(ws + OFS_MEAN);
    float* cvecv   = (float*)(ws + OFS_CVEC);
    float* cbv     = (float*)(ws + OFS_CB);
    float* dinvv   = (float*)(ws + OFS_DINV);
    float* gatev   = (float*)(ws + OFS_GATE);
    float* attv    = (float*)(ws + OFS_ATT);
    float* pooledv = (float*)(ws + OFS_POOL);

    u16*   xbf  = (u16*)(ws + OFS_RA);
    u16*   a1b  = (u16*)(ws + OFS_RA);                 // after f1
    u16*   a2b  = (u16*)(ws + OFS_RA + 8388608);
    float* facc = (float*)(ws + OFS_RA);               // after adjm
    u16*   h1   = (u16*)(ws + OFS_RB);
    u16*   tt   = (u16*)(ws + OFS_RB);                 // after f2
    u16*   h2   = (u16*)(ws + OFS_RC);
    u16*   x1   = (u16*)(ws + OFS_RC);                 // after f3
    u16*   g1   = (u16*)(ws + OFS_RC);                 // after cheb2
    u16*   g2   = (u16*)(ws + OFS_RC + 2097152);
    u16*   fea  = (u16*)(ws + OFS_RD);
    u16*   x2   = (u16*)(ws + OFS_RD);                 // after cheb1
    u16*   abf  = (u16*)(ws + OFS_RE);
    u16*   tcat = (u16*)(ws + OFS_RF);                 // [8192][2048] = T1..T4

    // ---- all weight conversions in one dispatch -----------------------------
    CvtJobs J;
    auto setjob = [&](int i, const float* s, u16* d, int K, int N, int Kp, int ld,
                      long sb, long db, int gx, int gy, int gz) {
        J.src[i] = s; J.dst[i] = d; J.K[i] = K; J.N[i] = N; J.Kpad[i] = Kp; J.ldD[i] = ld;
        J.sBS[i] = sb; J.dBS[i] = db; J.gx[i] = gx; J.gy[i] = gy;
        J.cum[i + 1] = J.cum[i] + gx * gy * gz;
    };
    J.cum[0] = 0;
    setjob(0,  Wf1, wf1t, 1024, 784, 1024, 1024, 0, 0, 32, 25, 1);
    setjob(1,  Wf2, wf2t, 784, 512, 800, 800, 0, 0, 25, 16, 1);
    setjob(2,  Wf3, wf3t, 512, 512, 512, 512, 0, 0, 16, 16, 1);
    setjob(3,  Wa1, wa1t, 512, 512, 512, 512, 0, 0, 16, 16, 1);
    setjob(4,  Wa2, wa2t, 512, 384, 512, 512, 0, 0, 16, 12, 1);
    setjob(5,  Wg1, wg1t0, 512, 512, 512, 512, 0, 0, 16, 16, 1);
    setjob(6,  Wg1 + 262144, wg1c, 512, 512, 512, 2048, 262144, 512, 16, 16, 4);
    setjob(7,  Wg2, wg2t0, 512, 384, 512, 512, 0, 0, 16, 12, 1);
    setjob(8,  Wg2 + 196608, wg2c, 512, 384, 512, 2048, 196608, 512, 16, 12, 4);
    setjob(9,  Wp1, wp1t, 384, 128, 384, 384, 0, 0, 12, 4, 1);
    setjob(10, Wp2, wp2t, 128, 64, 128, 128, 0, 0, 4, 2, 1);
    cvtT_all<<<J.cum[11], dim3(32, 8), 0, stream>>>(J);

    maskcvt_k<<<8192, 256, 0, stream>>>(inp, xbf, maskv);

    // fe_extrator
    gemm_bt<3, 64><<<dim3(13, 64, 1), 256, 0, stream>>>(xbf, wf1t, nullptr, h1, bf1, 0, maskv,
        nullptr, 0, 0, 8192, 784, 1024, 1024, 1024, 800, 0, 0, 0);
    gemm_bt<3, 64><<<dim3(8, 64, 1), 256, 0, stream>>>(h1, wf2t, nullptr, h2, bf2, 0, maskv,
        nullptr, 0, 0, 8192, 512, 800, 800, 800, 512, 0, 0, 0);
    gemm_bt<3, 64><<<dim3(8, 64, 1), 256, 0, stream>>>(h2, wf3t, nullptr, fea, bf3, 0, maskv,
        nullptr, 0, 0, 8192, 512, 512, 512, 512, 512, 0, 0, 0);

    // c vector + per-batch bias for adj layer 1
    zero_k<<<16, 256, 0, stream>>>(meanv, 8 * 512);
    colmean_k<<<dim3(8, 8), 512, 0, stream>>>(fea, meanv);
    cvec8_k<<<8, 512, 0, stream>>>(meanv, maskv, Wc, bc, cvecv);
    cb64_k<<<dim3(8, 8), 256, 0, stream>>>(cvecv, Wa1, ba1, cbv);

    // adj net
    gemm_bt<3, 64><<<dim3(8, 64, 1), 256, 0, stream>>>(fea, wa1t, nullptr, a1b, cbv, 512, maskv,
        nullptr, 0, 0, 8192, 512, 512, 512, 512, 512, 0, 0, 0);
    gemm_bt<3, 64><<<dim3(6, 64, 1), 256, 0, stream>>>(a1b, wa2t, nullptr, a2b, ba2, 0, maskv,
        nullptr, 0, 0, 8192, 384, 512, 512, 512, 384, 0, 0, 0);

    // adjacency, degree, Lhat (in place)
    gemm_bt<4, 64><<<dim3(16, 8, 8), 256, 0, stream>>>(a2b, a2b, nullptr, abf, nullptr, 0, maskv,
        nullptr, 0, 0, 1024, 1024, 384, 384, 384, 1024, 393216, 393216, 1048576);
    dinv_k<<<8192, 256, 0, stream>>>(abf, dinvv);
    lhat_k<<<8192, 256, 0, stream>>>(abf, dinvv);

    // ChebConv: T0 separate, T1..T4 K-concat in tcat; out = T0@W0 + Tcat@Wcat + b
    auto cheb = [&](const u16* T0, const u16* W0, const u16* Wcat, int Wn,
                    const float* bias, u16* outb, float* fa) {
        const dim3 gL(8, 8, 8);
        const dim3 gT0(8, 16, 8);     // transpose [1024][512] per batch
        const dim3 gTc(8, 16, 8);     // transpose [1024][512] slice of tcat
        // tt = T0^T
        tranb64_k<<<gT0, 256, 0, stream>>>(T0, tt, 512, 1024, 524288, 524288);
        // T1 = Lhat @ T0
        gemm_bt<5, 64><<<gL, 256, 0, stream>>>(abf, tt, nullptr, tcat, nullptr, 0, nullptr,
            nullptr, 0, 0, 1024, 512, 1024, 1024, 1024, 2048, 1048576, 524288, 2097152);
        tranb64_k<<<gTc, 256, 0, stream>>>(tcat, tt, 2048, 1024, 2097152, 524288);
        // T2 = 2 Lhat T1 - T0
        gemm_bt<6, 64><<<gL, 256, 0, stream>>>(abf, tt, nullptr, tcat + 512, nullptr, 0, nullptr,
            T0, 512, 524288, 1024, 512, 1024, 1024, 1024, 2048, 1048576, 524288, 2097152);
        tranb64_k<<<gTc, 256, 0, stream>>>(tcat + 512, tt, 2048, 1024, 2097152, 524288);
        // T3 = 2 Lhat T2 - T1
        gemm_bt<6, 64><<<gL, 256, 0, stream>>>(abf, tt, nullptr, tcat + 1024, nullptr, 0, nullptr,
            tcat, 2048, 2097152, 1024, 512, 1024, 1024, 1024, 2048, 1048576, 524288, 2097152);
        tranb64_k<<<gTc, 256, 0, stream>>>(tcat + 1024, tt, 2048, 1024, 2097152, 524288);
        // T4 = 2 Lhat T3 - T2
        gemm_bt<6, 64><<<gL, 256, 0, stream>>>(abf, tt, nullptr, tcat + 1536, nullptr, 0, nullptr,
            tcat + 512, 2048, 2097152, 1024, 512, 1024, 1024, 1024, 2048, 1048576, 524288, 2097152);
        // facc = T0 @ W0 ; out = relu(facc + Tcat @ Wcat + bias)
        gemm_bt<0, 64><<<dim3(Wn / 64, 64, 1), 256, 0, stream>>>(T0, W0, fa, nullptr, nullptr, 0,
            nullptr, nullptr, 0, 0, 8192, Wn, 512, 512, 512, Wn, 0, 0, 0);
        gemm_bt<2, 64><<<dim3(Wn / 64, 64, 1), 256, 0, stream>>>(tcat, Wcat, fa, outb, bias, 0,
            nullptr, nullptr, 0, 0, 8192, Wn, 2048, 2048, 2048, Wn, 0, 0, 0);
    };

    cheb(fea, wg1t0, wg1c, 512, bg1, x1, facc);
    cheb(x1,  wg2t0, wg2c, 384, bg2, x2, facc);

    // attention gate net + pooling tail
    gemm_bt<3, 64><<<dim3(2, 64, 1), 256, 0, stream>>>(x2, wp1t, nullptr, g1, bp1, 0, nullptr,
        nullptr, 0, 0, 8192, 128, 384, 384, 384, 128, 0, 0, 0);
    gemm_bt<3, 64><<<dim3(1, 64, 1), 256, 0, stream>>>(g1, wp2t, nullptr, g2, bp2, 0, nullptr,
        nullptr, 0, 0, 8192, 64, 128, 128, 128, 64, 0, 0, 0);
    gate_k<<<2048, 256, 0, stream>>>(g2, Wp3, bp3, maskv, gatev);
    attw_k<<<8, 256, 0, stream>>>(gatev, attv);
    zero_k<<<12, 256, 0, stream>>>(pooledv, 8 * 384);
    wsum_k<<<dim3(8, 8), 384, 0, stream>>>(attv, x2, pooledv);
    final8_k<<<8, 256, 0, stream>>>(pooledv, Wm1, bm1, Wm2, bm2, (float*)d_out);
}

// Round 9
// 580.717 us; speedup vs baseline: 1.5325x; 1.2153x over previous
//
#include <hip/hip_runtime.h>
#include <hip/hip_bf16.h>

typedef unsigned short u16;
typedef unsigned long long u64;
typedef float f32x4 __attribute__((ext_vector_type(4)));
typedef short s16x8 __attribute__((ext_vector_type(8)));

__device__ __forceinline__ float b2f(u16 u) {
    unsigned int x = ((unsigned int)u) << 16;
    return __builtin_bit_cast(float, x);
}
__device__ __forceinline__ u16 f2b(float f) {
    unsigned int x = __builtin_bit_cast(unsigned int, f);
    unsigned int lsb = (x >> 16) & 1u;
    x += 0x7fffu + lsb;                 // RNE; inputs are finite
    return (u16)(x >> 16);
}

#define GLOAD_LDS(g, l) __builtin_amdgcn_global_load_lds( \
    (const __attribute__((address_space(1))) void*)(g),   \
    (__attribute__((address_space(3))) void*)(l), 16, 0, 0)

// ---------------------------------------------------------------------------
// Batched GEMM: C[z,m,n] = sum_k A[z,m,k] * B[z,n,k]   (B stored [N][K])
// Tile 128xTN, BK=32, 256 threads = 4 waves, mfma_f32_16x16x32_bf16.
// Depth-2 pipeline: 3 LDS buffers, counted s_waitcnt vmcnt + raw s_barrier.
// 1D grid + XCD-locality decode (wgid%8 -> XCD round-robin assumed):
//   MODE 1 (batched ops): z = bid&7  -> batch z pinned to XCD z; A+B (3MB)
//           L2-resident per XCD. i=bid>>3: x = i & (2^nxs-1), y = i >> nxs.
//   MODE 2 (weight ops):  y = (bid&7)*8 + (i&7), x = i>>3 -> each XCD owns
//           8 contiguous M-panels; A streamed once, small B L2-cached.
// EPI: 0 Cf=acc                      2 Cb=relu(acc+Cf+bias)
//      3 Cb=relu(acc+bias)*mask      4 Cb=acc*mask[row]*mask[col]
//      5 Cb=acc                      6 Cb=2*acc - prev2
// ---------------------------------------------------------------------------
template<int EPI, int TN, int MODE>
__global__ __launch_bounds__(256)
void gemm_bt(const u16* __restrict__ A, const u16* __restrict__ B,
             float* __restrict__ Cf, u16* __restrict__ Cb,
             const float* __restrict__ bias, int biasBStride,
             const float* __restrict__ mask,
             const u16* __restrict__ prev2, int ldp, long pBS,
             int M, int N, int K, int lda, int ldb, int ldc,
             long aBS, long bBS, long cBS, int nxs)
{
    constexpr int NJ = (TN == 128) ? 4 : 2;
    __shared__ u16 As[3][128 * 32];
    __shared__ u16 Bs[3][TN * 32];
    const int tid  = threadIdx.x;
    const int lane = tid & 63;
    const int bid  = blockIdx.x;
    int xq, yq, zq;
    if (MODE == 1) {
        zq = bid & 7;
        const int i = bid >> 3;
        xq = i & ((1 << nxs) - 1);
        yq = i >> nxs;
    } else {
        zq = 0;
        const int q = bid & 7, i = bid >> 3;
        yq = q * 8 + (i & 7);
        xq = i >> 3;
    }
    const int m0   = yq * 128;
    const int n0   = xq * TN;
    const int wm   = ((tid >> 7) & 1) * 64;
    const int wn   = ((tid >> 6) & 1) * (TN / 2);
    const int l15  = lane & 15;
    const int lg   = lane >> 4;
    const u16* Ab = A + (long)zq * aBS;
    const u16* Bb = B + (long)zq * bBS;

    f32x4 acc[4][NJ] = {};
    const int nt = K >> 5;

    auto stage = [&](int s, int t) {
        const int u0 = tid, u1 = tid + 256;
        GLOAD_LDS(Ab + (long)(m0 + (u0 >> 2)) * lda + t * 32 + (u0 & 3) * 8, &As[s][u0 * 8]);
        GLOAD_LDS(Ab + (long)(m0 + (u1 >> 2)) * lda + t * 32 + (u1 & 3) * 8, &As[s][u1 * 8]);
        GLOAD_LDS(Bb + (long)(n0 + (u0 >> 2)) * ldb + t * 32 + (u0 & 3) * 8, &Bs[s][u0 * 8]);
        if (TN == 128)
            GLOAD_LDS(Bb + (long)(n0 + (u1 >> 2)) * ldb + t * 32 + (u1 & 3) * 8, &Bs[s][u1 * 8]);
    };

    stage(0, 0);
    if (nt > 1) stage(1, 1);
    int cur = 0;
    for (int t = 0; t < nt; ++t) {
        if (t + 1 < nt) {
            if (TN == 128) asm volatile("s_waitcnt vmcnt(4) lgkmcnt(0)" ::: "memory");
            else           asm volatile("s_waitcnt vmcnt(3) lgkmcnt(0)" ::: "memory");
        } else {
            asm volatile("s_waitcnt vmcnt(0) lgkmcnt(0)" ::: "memory");
        }
        __builtin_amdgcn_s_barrier();
        s16x8 af[4], bg[NJ];
        #pragma unroll
        for (int i = 0; i < 4; ++i)
            af[i] = *(const s16x8*)&As[cur][(wm + i * 16 + l15) * 32 + lg * 8];
        #pragma unroll
        for (int j = 0; j < NJ; ++j)
            bg[j] = *(const s16x8*)&Bs[cur][(wn + j * 16 + l15) * 32 + lg * 8];
        if (t + 2 < nt) stage(cur == 0 ? 2 : cur - 1, t + 2);  // (cur+2)%3
        #pragma unroll
        for (int i = 0; i < 4; ++i)
            #pragma unroll
            for (int j = 0; j < NJ; ++j)
                acc[i][j] = __builtin_amdgcn_mfma_f32_16x16x32_bf16(bg[j], af[i], acc[i][j], 0, 0, 0);
        cur = (cur == 2) ? 0 : cur + 1;
    }

    const long cb0 = (long)zq * cBS;
    #pragma unroll
    for (int i = 0; i < 4; ++i) {
        const int row = m0 + wm + i * 16 + l15;
        float rm = 1.f;
        if ((EPI == 3 || EPI == 4) && mask) rm = mask[zq * M + row];
        #pragma unroll
        for (int j = 0; j < NJ; ++j) {
            const int nb = n0 + wn + j * 16 + lg * 4;
            if (nb >= N) continue;
            const long idx = cb0 + (long)row * ldc + nb;
            if (EPI == 0) {
                *(float4*)&Cf[idx] = make_float4(acc[i][j][0], acc[i][j][1], acc[i][j][2], acc[i][j][3]);
            } else {
                float x[4];
                if (EPI == 2) {
                    const float4 cv = *(const float4*)&Cf[idx];
                    x[0] = fmaxf(acc[i][j][0] + cv.x + bias[nb + 0], 0.f);
                    x[1] = fmaxf(acc[i][j][1] + cv.y + bias[nb + 1], 0.f);
                    x[2] = fmaxf(acc[i][j][2] + cv.z + bias[nb + 2], 0.f);
                    x[3] = fmaxf(acc[i][j][3] + cv.w + bias[nb + 3], 0.f);
                } else if (EPI == 3) {
                    const int bb0 = biasBStride ? ((zq * M + row) >> 10) * biasBStride : 0;
                    #pragma unroll
                    for (int r = 0; r < 4; ++r) {
                        float v = fmaxf(acc[i][j][r] + bias[bb0 + nb + r], 0.f);
                        x[r] = mask ? v * rm : v;
                    }
                } else if (EPI == 4) {
                    #pragma unroll
                    for (int r = 0; r < 4; ++r)
                        x[r] = acc[i][j][r] * rm * mask[zq * N + nb + r];
                } else if (EPI == 5) {
                    #pragma unroll
                    for (int r = 0; r < 4; ++r) x[r] = acc[i][j][r];
                } else {
                    const u64 pv = *(const u64*)&prev2[(long)zq * pBS + (long)row * ldp + nb];
                    #pragma unroll
                    for (int r = 0; r < 4; ++r)
                        x[r] = 2.f * acc[i][j][r] - b2f((u16)(pv >> (16 * r)));
                }
                u64 pk = (u64)f2b(x[0]) | ((u64)f2b(x[1]) << 16)
                       | ((u64)f2b(x[2]) << 32) | ((u64)f2b(x[3]) << 48);
                *(u64*)&Cb[idx] = pk;
            }
        }
    }
}

// ---------------------------------------------------------------------------
// all 11 weight conversions (fp32 [K][N] -> bf16 [n][ldD], zero-padded) in ONE
// dispatch: flat block id -> job lookup via cumulative block counts.
// ---------------------------------------------------------------------------
struct CvtJobs {
    const float* src[11];
    u16* dst[11];
    int K[11], N[11], Kpad[11], ldD[11];
    long sBS[11], dBS[11];
    int gx[11], gy[11];
    int cum[12];
};

__global__ void cvtT_all(CvtJobs J)
{
    __shared__ float t[32][33];
    const int bid = blockIdx.x;
    int j = 0;
    #pragma unroll
    for (int q = 0; q < 11; ++q) if (bid >= J.cum[q + 1]) j = q + 1;
    const int local = bid - J.cum[j];
    const int bx = local % J.gx[j];
    const int rem = local / J.gx[j];
    const int by = rem % J.gy[j];
    const int bz = rem / J.gy[j];
    const float* src = J.src[j] + (long)bz * J.sBS[j];
    u16* dst = J.dst[j] + (long)bz * J.dBS[j];
    const int K = J.K[j], N = J.N[j], Kpad = J.Kpad[j], ldD = J.ldD[j];
    const int tx = threadIdx.x, ty = threadIdx.y;
    const int k0 = bx * 32, n0 = by * 32;
    #pragma unroll
    for (int rr = ty; rr < 32; rr += 8) {
        int k = k0 + rr, n = n0 + tx;
        t[rr][tx] = (k < K && n < N) ? src[(long)k * N + n] : 0.f;
    }
    __syncthreads();
    #pragma unroll
    for (int rr = ty; rr < 32; rr += 8) {
        int n = n0 + rr, k = k0 + tx;
        if (n < N && k < Kpad) dst[(long)n * ldD + k] = f2b(t[tx][rr]);
    }
}

// bf16 [R][C] (row stride lds_) -> bf16 [C][R] (row stride ldd_), batched.
// 64x64 tiles, u64 (4xbf16) loads and stores; LDS pad 2 -> <=2-way conflicts.
__global__ __launch_bounds__(256)
void tranb64_k(const u16* __restrict__ src, u16* __restrict__ dst,
               int lds_, int ldd_, long sBS, long dBS)
{
    __shared__ u16 t[64][66];
    const int tid = threadIdx.x;
    const int r0 = blockIdx.y * 64, c0 = blockIdx.x * 64;
    src += (long)blockIdx.z * sBS;
    dst += (long)blockIdx.z * dBS;
    #pragma unroll
    for (int q = 0; q < 4; ++q) {
        const int lin = tid + q * 256;
        const int row = lin >> 4, c4 = (lin & 15) * 4;
        const u64 v = *(const u64*)&src[(long)(r0 + row) * lds_ + c0 + c4];
        t[row][c4 + 0] = (u16)(v);
        t[row][c4 + 1] = (u16)(v >> 16);
        t[row][c4 + 2] = (u16)(v >> 32);
        t[row][c4 + 3] = (u16)(v >> 48);
    }
    __syncthreads();
    #pragma unroll
    for (int q = 0; q < 4; ++q) {
        const int lin = tid + q * 256;
        const int col = lin >> 4, r4 = (lin & 15) * 4;
        u64 v = (u64)t[r4 + 0][col] | ((u64)t[r4 + 1][col] << 16)
              | ((u64)t[r4 + 2][col] << 32) | ((u64)t[r4 + 3][col] << 48);
        *(u64*)&dst[(long)(c0 + col) * ldd_ + r0 + r4] = v;
    }
}

// fused mask + fp32->bf16 convert: one block per node row
__global__ void maskcvt_k(const float* __restrict__ inp, u16* __restrict__ xbf,
                          float* __restrict__ mask)
{
    const int row = blockIdx.x, tid = threadIdx.x;
    const long base = (long)row * 1024 + tid * 4;
    float4 v = *(const float4*)&inp[base];
    u64 pk = (u64)f2b(v.x) | ((u64)f2b(v.y) << 16)
           | ((u64)f2b(v.z) << 32) | ((u64)f2b(v.w) << 48);
    *(u64*)&xbf[base] = pk;
    float s = v.x + v.y + v.z + v.w;
    __shared__ float red[256];
    red[tid] = s; __syncthreads();
    for (int o = 128; o > 0; o >>= 1) { if (tid < o) red[tid] += red[tid + o]; __syncthreads(); }
    if (tid == 0) mask[row] = (red[0] != 0.f) ? 1.f : 0.f;
}

__global__ void zero_k(float* __restrict__ p, int n)
{
    const int i = blockIdx.x * 256 + threadIdx.x;
    if (i < n) p[i] = 0.f;
}

// partial column sums of fea into mean (pre-zeroed), 64 blocks
__global__ void colmean_k(const u16* __restrict__ fea, float* __restrict__ mean)
{
    const int b = blockIdx.y, ch = blockIdx.x, f = threadIdx.x;   // 512
    const u16* p = fea + (long)b * 1024 * 512 + (long)ch * 128 * 512 + f;
    float s = 0.f;
    #pragma unroll 4
    for (int n = 0; n < 128; ++n) s += b2f(p[n * 512]);
    atomicAdd(&mean[b * 512 + f], s);
}

// c = relu((colsum/numel) @ Wc + bc), grid 8, 512 threads
__global__ void cvec8_k(const float* __restrict__ mean, const float* __restrict__ mask,
                        const float* __restrict__ Wc, const float* __restrict__ bc,
                        float* __restrict__ c)
{
    const int b = blockIdx.x, tid = threadIdx.x;
    __shared__ float red[512];
    __shared__ float mn[512];
    red[tid] = mask[b * 1024 + tid] + mask[b * 1024 + 512 + tid];
    __syncthreads();
    for (int o = 256; o > 0; o >>= 1) { if (tid < o) red[tid] += red[tid + o]; __syncthreads(); }
    const float numel = red[0];
    __syncthreads();
    mn[tid] = mean[b * 512 + tid] / numel;
    __syncthreads();
    const int o = tid & 127, q = tid >> 7;
    float cs = 0.f;
    #pragma unroll 8
    for (int f = q * 128; f < q * 128 + 128; ++f) cs += mn[f] * Wc[f * 128 + o];
    red[tid] = cs;
    __syncthreads();
    if (tid < 256) red[tid] += red[tid + 256];
    __syncthreads();
    if (tid < 128) c[b * 128 + tid] = fmaxf(red[tid] + red[tid + 128] + bc[tid], 0.f);
}

// cb[b][o] = ba1[o] + sum_j c[b][j]*Wa1[512+j][o]; grid (8 oc-chunks, 8 batch)
__global__ void cb64_k(const float* __restrict__ c, const float* __restrict__ Wa1,
                       const float* __restrict__ ba1, float* __restrict__ cb)
{
    const int oc = blockIdx.x, b = blockIdx.y, tid = threadIdx.x;  // 256
    __shared__ float cC[128];
    __shared__ float red[256];
    if (tid < 128) cC[tid] = c[b * 128 + tid];
    __syncthreads();
    const int o = tid & 63, part = tid >> 6;     // 4 partials per output
    const float* w = Wa1 + (long)(512 + part * 32) * 512 + oc * 64 + o;
    float s = 0.f;
    #pragma unroll 8
    for (int j = 0; j < 32; ++j) s += cC[part * 32 + j] * w[j * 512];
    red[tid] = s;
    __syncthreads();
    if (tid < 64) {
        float tot = red[tid] + red[tid + 64] + red[tid + 128] + red[tid + 192]
                  + ba1[oc * 64 + tid];
        cb[b * 512 + oc * 64 + tid] = tot;
    }
}

__global__ void dinv_k(const u16* __restrict__ Abf, float* __restrict__ dinv)
{
    const int row = blockIdx.x, tid = threadIdx.x;
    const u16* p = Abf + (long)row * 1024 + tid * 4;
    float s = b2f(p[0]) + b2f(p[1]) + b2f(p[2]) + b2f(p[3]);
    __shared__ float red[256];
    red[tid] = s; __syncthreads();
    for (int o = 128; o > 0; o >>= 1) { if (tid < o) red[tid] += red[tid + o]; __syncthreads(); }
    if (tid == 0) {
        float d = red[0];
        dinv[row] = d > 0.f ? rsqrtf(fmaxf(d, 1e-30f)) : 0.f;
    }
}

__global__ void lhat_k(u16* __restrict__ Abf, const float* __restrict__ dinv)
{
    const long e0 = ((long)blockIdx.x * 256 + threadIdx.x) * 4;
    const int b = (int)(e0 >> 20);
    const int i = (int)((e0 >> 10) & 1023);
    const int j = (int)(e0 & 1023);
    const float di = dinv[b * 1024 + i];
    u16* p = Abf + e0;
    #pragma unroll
    for (int t = 0; t < 4; ++t) {
        float v = -di * b2f(p[t]) * dinv[b * 1024 + j + t];
        p[t] = f2b(v);
    }
}

__global__ void gate_k(const u16* __restrict__ g2, const float* __restrict__ Wp3,
                       const float* __restrict__ bp3, const float* __restrict__ mask,
                       float* __restrict__ gate)
{
    const int row = blockIdx.x * 4 + (threadIdx.x >> 6);
    const int lane = threadIdx.x & 63;
    float v = b2f(g2[row * 64 + lane]) * Wp3[lane];
    for (int o = 32; o > 0; o >>= 1) v += __shfl_xor(v, o, 64);
    if (lane == 0)
        gate[row] = (mask[row] > 0.f) ? tanhf(v + bp3[0]) : -1e9f;
}

// per-batch softmax over 1024 gates -> att
__global__ void attw_k(const float* __restrict__ gate, float* __restrict__ att)
{
    const int b = blockIdx.x, tid = threadIdx.x;  // 256
    const float* g = gate + b * 1024;
    float4 v = *(const float4*)&g[tid * 4];
    __shared__ float red[256];
    red[tid] = fmaxf(fmaxf(v.x, v.y), fmaxf(v.z, v.w));
    __syncthreads();
    for (int o = 128; o > 0; o >>= 1) { if (tid < o) red[tid] = fmaxf(red[tid], red[tid + o]); __syncthreads(); }
    const float mx = red[0];
    __syncthreads();
    float e0 = expf(v.x - mx), e1 = expf(v.y - mx), e2 = expf(v.z - mx), e3 = expf(v.w - mx);
    red[tid] = e0 + e1 + e2 + e3;
    __syncthreads();
    for (int o = 128; o > 0; o >>= 1) { if (tid < o) red[tid] += red[tid + o]; __syncthreads(); }
    const float zi = 1.f / red[0];
    float4 w = { e0 * zi, e1 * zi, e2 * zi, e3 * zi };
    *(float4*)&att[b * 1024 + tid * 4] = w;
}

// partial weighted sums into pooled (pre-zeroed), 64 blocks
__global__ void wsum_k(const float* __restrict__ att, const u16* __restrict__ x2,
                       float* __restrict__ pooled)
{
    const int b = blockIdx.y, ch = blockIdx.x, o = threadIdx.x;  // 384
    const u16* xb = x2 + (long)b * 1024 * 384 + (long)ch * 128 * 384 + o;
    const float* ab = att + b * 1024 + ch * 128;
    float s = 0.f;
    #pragma unroll 4
    for (int n = 0; n < 128; ++n) s += ab[n] * b2f(xb[n * 384]);
    atomicAdd(&pooled[b * 384 + o], s);
}

// output MLP, one block per batch
__global__ void final8_k(const float* __restrict__ pooled, const float* __restrict__ Wm1,
                         const float* __restrict__ bm1, const float* __restrict__ Wm2,
                         const float* __restrict__ bm2, float* __restrict__ out)
{
    __shared__ float pl[384];
    __shared__ float wred[4];
    const int b = blockIdx.x, tid = threadIdx.x;  // 256
    if (tid < 192) {
        pl[tid] = pooled[b * 384 + tid];
        pl[tid + 192] = pooled[b * 384 + tid + 192];
    }
    __syncthreads();
    float s = bm1[tid];
    for (int f = 0; f < 384; ++f) s += pl[f] * Wm1[f * 256 + tid];
    float h = fmaxf(s, 0.f) * Wm2[tid];
    for (int off = 32; off > 0; off >>= 1) h += __shfl_xor(h, off, 64);
    if ((tid & 63) == 0) wred[tid >> 6] = h;
    __syncthreads();
    if (tid == 0)
        out[b] = 1.f / (1.f + expf(-(wred[0] + wred[1] + wred[2] + wred[3] + bm2[0])));
}

// ---------------------------------------------------------------------------
// workspace layout
// ---------------------------------------------------------------------------
constexpr size_t OFS_WF1T = 0;                               // 832x1024 bf16
constexpr size_t OFS_WF2T = OFS_WF1T + 832ull * 1024 * 2;    // 512x800
constexpr size_t OFS_WF3T = OFS_WF2T + 512ull * 800 * 2;     // 512x512
constexpr size_t OFS_WA1T = OFS_WF3T + 512ull * 512 * 2;
constexpr size_t OFS_WA2T = OFS_WA1T + 512ull * 512 * 2;     // 384x512
constexpr size_t OFS_WG1T0 = OFS_WA2T + 384ull * 512 * 2;    // 512x512
constexpr size_t OFS_WG1C  = OFS_WG1T0 + 512ull * 512 * 2;   // 512x2048
constexpr size_t OFS_WG2T0 = OFS_WG1C + 512ull * 2048 * 2;   // 384x512
constexpr size_t OFS_WG2C  = OFS_WG2T0 + 384ull * 512 * 2;   // 384x2048
constexpr size_t OFS_WP1T  = OFS_WG2C + 384ull * 2048 * 2;   // 128x384
constexpr size_t OFS_WP2T  = OFS_WP1T + 128ull * 384 * 2;    // 64x128
constexpr size_t OFS_MASK  = OFS_WP2T + 64ull * 128 * 2;
constexpr size_t OFS_MEAN  = OFS_MASK + 32768;
constexpr size_t OFS_CVEC  = OFS_MEAN + 16384;
constexpr size_t OFS_CB    = OFS_CVEC + 4096;
constexpr size_t OFS_DINV  = OFS_CB + 16384;
constexpr size_t OFS_GATE  = OFS_DINV + 32768;
constexpr size_t OFS_ATT   = OFS_GATE + 32768;
constexpr size_t OFS_POOL  = OFS_ATT + 32768;
constexpr size_t OFS_RA    = OFS_POOL + 16384;               // 16 MiB: xbf | a1,a2 | facc
constexpr size_t OFS_RB    = OFS_RA + 16777216;              // 12.5 MiB: h1 | tt
constexpr size_t OFS_RC    = OFS_RB + 13107200;              // 8 MiB: h2 | x1 | g1,g2
constexpr size_t OFS_RD    = OFS_RC + 8388608;               // 8 MiB: fea | x2
constexpr size_t OFS_RE    = OFS_RD + 8388608;               // 16 MiB: abf (Lhat)
constexpr size_t OFS_RF    = OFS_RE + 16777216;              // 32 MiB: Tcat (T1..T4)
constexpr size_t WS_TOTAL  = OFS_RF + 33554432;              // ~100.9 MiB

extern "C" void kernel_launch(void* const* d_in, const int* in_sizes, int n_in,
                              void* d_out, int out_size, void* d_ws, size_t ws_size,
                              hipStream_t stream)
{
    const float* inp = (const float*)d_in[0];
    const float* Wf1 = (const float*)d_in[2];  const float* bf1 = (const float*)d_in[3];
    const float* Wf2 = (const float*)d_in[4];  const float* bf2 = (const float*)d_in[5];
    const float* Wf3 = (const float*)d_in[6];  const float* bf3 = (const float*)d_in[7];
    const float* Wc  = (const float*)d_in[8];  const float* bc  = (const float*)d_in[9];
    const float* Wa1 = (const float*)d_in[10]; const float* ba1 = (const float*)d_in[11];
    const float* Wa2 = (const float*)d_in[12]; const float* ba2 = (const float*)d_in[13];
    const float* Wg1 = (const float*)d_in[14]; const float* bg1 = (const float*)d_in[15];
    const float* Wg2 = (const float*)d_in[16]; const float* bg2 = (const float*)d_in[17];
    const float* Wp1 = (const float*)d_in[18]; const float* bp1 = (const float*)d_in[19];
    const float* Wp2 = (const float*)d_in[20]; const float* bp2 = (const float*)d_in[21];
    const float* Wp3 = (const float*)d_in[22]; const float* bp3 = (const float*)d_in[23];
    const float* Wm1 = (const float*)d_in[24]; const float* bm1 = (const float*)d_in[25];
    const float* Wm2 = (const float*)d_in[26]; const float* bm2 = (const float*)d_in[27];

    if (ws_size < WS_TOTAL) return;
    char* ws = (char*)d_ws;

    u16* wf1t  = (u16*)(ws + OFS_WF1T);
    u16* wf2t  = (u16*)(ws + OFS_WF2T);
    u16* wf3t  = (u16*)(ws + OFS_WF3T);
    u16* wa1t  = (u16*)(ws + OFS_WA1T);
    u16* wa2t  = (u16*)(ws + OFS_WA2T);
    u16* wg1t0 = (u16*)(ws + OFS_WG1T0);
    u16* wg1c  = (u16*)(ws + OFS_WG1C);
    u16* wg2t0 = (u16*)(ws + OFS_WG2T0);
    u16* wg2c  = (u16*)(ws + OFS_WG2C);
    u16* wp1t  = (u16*)(ws + OFS_WP1T);
    u16* wp2t  = (u16*)(ws + OFS_WP2T);
    float* maskv   = (float*)(ws + OFS_MASK);
    float* meanv   = (float*)(ws + OFS_MEAN);
    float* cvecv   = (float*)(ws + OFS_CVEC);
    float* cbv     = (float*)(ws + OFS_CB);
    float* dinvv   = (float*)(ws + OFS_DINV);
    float* gatev   = (float*)(ws + OFS_GATE);
    float* attv    = (float*)(ws + OFS_ATT);
    float* pooledv = (float*)(ws + OFS_POOL);

    u16*   xbf  = (u16*)(ws + OFS_RA);
    u16*   a1b  = (u16*)(ws + OFS_RA);                 // after f1
    u16*   a2b  = (u16*)(ws + OFS_RA + 8388608);
    float* facc = (float*)(ws + OFS_RA);               // after adjm
    u16*   h1   = (u16*)(ws + OFS_RB);
    u16*   tt   = (u16*)(ws + OFS_RB);                 // after f2
    u16*   h2   = (u16*)(ws + OFS_RC);
    u16*   x1   = (u16*)(ws + OFS_RC);                 // after f3
    u16*   g1   = (u16*)(ws + OFS_RC);                 // after cheb2
    u16*   g2   = (u16*)(ws + OFS_RC + 2097152);
    u16*   fea  = (u16*)(ws + OFS_RD);
    u16*   x2   = (u16*)(ws + OFS_RD);                 // after cheb1
    u16*   abf  = (u16*)(ws + OFS_RE);
    u16*   tcat = (u16*)(ws + OFS_RF);                 // [8192][2048] = T1..T4

    // ---- all weight conversions in one dispatch -----------------------------
    CvtJobs J;
    auto setjob = [&](int i, const float* s, u16* d, int K, int N, int Kp, int ld,
                      long sb, long db, int gx, int gy, int gz) {
        J.src[i] = s; J.dst[i] = d; J.K[i] = K; J.N[i] = N; J.Kpad[i] = Kp; J.ldD[i] = ld;
        J.sBS[i] = sb; J.dBS[i] = db; J.gx[i] = gx; J.gy[i] = gy;
        J.cum[i + 1] = J.cum[i] + gx * gy * gz;
    };
    J.cum[0] = 0;
    setjob(0,  Wf1, wf1t, 1024, 784, 1024, 1024, 0, 0, 32, 25, 1);
    setjob(1,  Wf2, wf2t, 784, 512, 800, 800, 0, 0, 25, 16, 1);
    setjob(2,  Wf3, wf3t, 512, 512, 512, 512, 0, 0, 16, 16, 1);
    setjob(3,  Wa1, wa1t, 512, 512, 512, 512, 0, 0, 16, 16, 1);
    setjob(4,  Wa2, wa2t, 512, 384, 512, 512, 0, 0, 16, 12, 1);
    setjob(5,  Wg1, wg1t0, 512, 512, 512, 512, 0, 0, 16, 16, 1);
    setjob(6,  Wg1 + 262144, wg1c, 512, 512, 512, 2048, 262144, 512, 16, 16, 4);
    setjob(7,  Wg2, wg2t0, 512, 384, 512, 512, 0, 0, 16, 12, 1);
    setjob(8,  Wg2 + 196608, wg2c, 512, 384, 512, 2048, 196608, 512, 16, 12, 4);
    setjob(9,  Wp1, wp1t, 384, 128, 384, 384, 0, 0, 12, 4, 1);
    setjob(10, Wp2, wp2t, 128, 64, 128, 128, 0, 0, 4, 2, 1);
    cvtT_all<<<J.cum[11], dim3(32, 8), 0, stream>>>(J);

    maskcvt_k<<<8192, 256, 0, stream>>>(inp, xbf, maskv);

    // fe_extrator  (MODE 2: weight GEMMs, y-partitioned per XCD)
    gemm_bt<3, 64, 2><<<13 * 64, 256, 0, stream>>>(xbf, wf1t, nullptr, h1, bf1, 0, maskv,
        nullptr, 0, 0, 8192, 784, 1024, 1024, 1024, 800, 0, 0, 0, 0);
    gemm_bt<3, 64, 2><<<8 * 64, 256, 0, stream>>>(h1, wf2t, nullptr, h2, bf2, 0, maskv,
        nullptr, 0, 0, 8192, 512, 800, 800, 800, 512, 0, 0, 0, 0);
    gemm_bt<3, 64, 2><<<8 * 64, 256, 0, stream>>>(h2, wf3t, nullptr, fea, bf3, 0, maskv,
        nullptr, 0, 0, 8192, 512, 512, 512, 512, 512, 0, 0, 0, 0);

    // c vector + per-batch bias for adj layer 1
    zero_k<<<16, 256, 0, stream>>>(meanv, 8 * 512);
    colmean_k<<<dim3(8, 8), 512, 0, stream>>>(fea, meanv);
    cvec8_k<<<8, 512, 0, stream>>>(meanv, maskv, Wc, bc, cvecv);
    cb64_k<<<dim3(8, 8), 256, 0, stream>>>(cvecv, Wa1, ba1, cbv);

    // adj net
    gemm_bt<3, 64, 2><<<8 * 64, 256, 0, stream>>>(fea, wa1t, nullptr, a1b, cbv, 512, maskv,
        nullptr, 0, 0, 8192, 512, 512, 512, 512, 512, 0, 0, 0, 0);
    gemm_bt<3, 64, 2><<<6 * 64, 256, 0, stream>>>(a1b, wa2t, nullptr, a2b, ba2, 0, maskv,
        nullptr, 0, 0, 8192, 384, 512, 512, 512, 384, 0, 0, 0, 0);

    // adjacency, degree, Lhat (in place)  (MODE 1: batch z pinned to XCD z)
    gemm_bt<4, 64, 1><<<8 * 16 * 8, 256, 0, stream>>>(a2b, a2b, nullptr, abf, nullptr, 0, maskv,
        nullptr, 0, 0, 1024, 1024, 384, 384, 384, 1024, 393216, 393216, 1048576, 4);
    dinv_k<<<8192, 256, 0, stream>>>(abf, dinvv);
    lhat_k<<<8192, 256, 0, stream>>>(abf, dinvv);

    // ChebConv: T0 separate, T1..T4 K-concat in tcat; out = T0@W0 + Tcat@Wcat + b
    auto cheb = [&](const u16* T0, const u16* W0, const u16* Wcat, int Wn,
                    const float* bias, u16* outb, float* fa) {
        const int gL = 8 * 8 * 8;     // MODE 1, nxs=3 (8 n-blocks), 8 m-blocks
        const dim3 gT0(8, 16, 8);     // transpose [1024][512] per batch
        const dim3 gTc(8, 16, 8);     // transpose [1024][512] slice of tcat
        // tt = T0^T
        tranb64_k<<<gT0, 256, 0, stream>>>(T0, tt, 512, 1024, 524288, 524288);
        // T1 = Lhat @ T0
        gemm_bt<5, 64, 1><<<gL, 256, 0, stream>>>(abf, tt, nullptr, tcat, nullptr, 0, nullptr,
            nullptr, 0, 0, 1024, 512, 1024, 1024, 1024, 2048, 1048576, 524288, 2097152, 3);
        tranb64_k<<<gTc, 256, 0, stream>>>(tcat, tt, 2048, 1024, 2097152, 524288);
        // T2 = 2 Lhat T1 - T0
        gemm_bt<6, 64, 1><<<gL, 256, 0, stream>>>(abf, tt, nullptr, tcat + 512, nullptr, 0, nullptr,
            T0, 512, 524288, 1024, 512, 1024, 1024, 1024, 2048, 1048576, 524288, 2097152, 3);
        tranb64_k<<<gTc, 256, 0, stream>>>(tcat + 512, tt, 2048, 1024, 2097152, 524288);
        // T3 = 2 Lhat T2 - T1
        gemm_bt<6, 64, 1><<<gL, 256, 0, stream>>>(abf, tt, nullptr, tcat + 1024, nullptr, 0, nullptr,
            tcat, 2048, 2097152, 1024, 512, 1024, 1024, 1024, 2048, 1048576, 524288, 2097152, 3);
        tranb64_k<<<gTc, 256, 0, stream>>>(tcat + 1024, tt, 2048, 1024, 2097152, 524288);
        // T4 = 2 Lhat T3 - T2
        gemm_bt<6, 64, 1><<<gL, 256, 0, stream>>>(abf, tt, nullptr, tcat + 1536, nullptr, 0, nullptr,
            tcat + 512, 2048, 2097152, 1024, 512, 1024, 1024, 1024, 2048, 1048576, 524288, 2097152, 3);
        // facc = T0 @ W0 ; out = relu(facc + Tcat @ Wcat + bias)
        gemm_bt<0, 64, 2><<<(Wn / 64) * 64, 256, 0, stream>>>(T0, W0, fa, nullptr, nullptr, 0,
            nullptr, nullptr, 0, 0, 8192, Wn, 512, 512, 512, Wn, 0, 0, 0, 0);
        gemm_bt<2, 64, 2><<<(Wn / 64) * 64, 256, 0, stream>>>(tcat, Wcat, fa, outb, bias, 0,
            nullptr, nullptr, 0, 0, 8192, Wn, 2048, 2048, 2048, Wn, 0, 0, 0, 0);
    };

    cheb(fea, wg1t0, wg1c, 512, bg1, x1, facc);
    cheb(x1,  wg2t0, wg2c, 384, bg2, x2, facc);

    // attention gate net + pooling tail
    gemm_bt<3, 64, 2><<<2 * 64, 256, 0, stream>>>(x2, wp1t, nullptr, g1, bp1, 0, nullptr,
        nullptr, 0, 0, 8192, 128, 384, 384, 384, 128, 0, 0, 0, 0);
    gemm_bt<3, 64, 2><<<1 * 64, 256, 0, stream>>>(g1, wp2t, nullptr, g2, bp2, 0, nullptr,
        nullptr, 0, 0, 8192, 64, 128, 128, 128, 64, 0, 0, 0, 0);
    gate_k<<<2048, 256, 0, stream>>>(g2, Wp3, bp3, maskv, gatev);
    attw_k<<<8, 256, 0, stream>>>(gatev, attv);
    zero_k<<<12, 256, 0, stream>>>(pooledv, 8 * 384);
    wsum_k<<<dim3(8, 8), 384, 0, stream>>>(attv, x2, pooledv);
    final8_k<<<8, 256, 0, stream>>>(pooledv, Wm1, bm1, Wm2, bm2, (float*)d_out);
}

// Round 10
// 579.974 us; speedup vs baseline: 1.5345x; 1.0013x over previous
//
#include <hip/hip_runtime.h>
#include <hip/hip_bf16.h>

typedef unsigned short u16;
typedef unsigned long long u64;
typedef float f32x4 __attribute__((ext_vector_type(4)));
typedef short s16x8 __attribute__((ext_vector_type(8)));

__device__ __forceinline__ float b2f(u16 u) {
    unsigned int x = ((unsigned int)u) << 16;
    return __builtin_bit_cast(float, x);
}
__device__ __forceinline__ u16 f2b(float f) {
    unsigned int x = __builtin_bit_cast(unsigned int, f);
    unsigned int lsb = (x >> 16) & 1u;
    x += 0x7fffu + lsb;                 // RNE; inputs are finite
    return (u16)(x >> 16);
}

#define GLOAD_LDS(g, l) __builtin_amdgcn_global_load_lds( \
    (const __attribute__((address_space(1))) void*)(g),   \
    (__attribute__((address_space(3))) void*)(l), 16, 0, 0)

// ---------------------------------------------------------------------------
// Batched GEMM: C[z,m,n] = sum_k A[z,m,k] * B[z,n,k]   (B stored [N][K])
// Tile 128xTN, BK=32, 256 threads = 4 waves, mfma_f32_16x16x32_bf16.
// Depth-2 pipeline: 3 LDS buffers, counted s_waitcnt vmcnt + raw s_barrier.
// LDS bank-conflict swizzle (rule #21: linear gload_lds dest + permuted
// SOURCE + same permutation on read): 16B chunk index c' = c ^ ((r^(r>>2))&3).
// Unswizzled [r][32k] row stride 64B put 16 fragment-read lanes on 2 bank-
// quads (8-way conflict, 2.94x); swizzle spreads 8 rows over all 32 banks
// (2-way = free). Staging coalescing unchanged (chunks permuted within row).
// 1D grid + XCD-locality decode (wgid%8 -> XCD round-robin assumed):
//   MODE 1 (batched ops): z = bid&7 -> batch z pinned to XCD z (A+B L2-res).
//   MODE 2 (weight ops):  y = (bid&7)*8 + (i&7), x = i>>3.
// EPI: 0 Cf=acc                      2 Cb=relu(acc+Cf+bias)
//      3 Cb=relu(acc+bias)*mask      4 Cb=acc*mask[row]*mask[col]
//      5 Cb=acc                      6 Cb=2*acc - prev2
// ---------------------------------------------------------------------------
template<int EPI, int TN, int MODE>
__global__ __launch_bounds__(256)
void gemm_bt(const u16* __restrict__ A, const u16* __restrict__ B,
             float* __restrict__ Cf, u16* __restrict__ Cb,
             const float* __restrict__ bias, int biasBStride,
             const float* __restrict__ mask,
             const u16* __restrict__ prev2, int ldp, long pBS,
             int M, int N, int K, int lda, int ldb, int ldc,
             long aBS, long bBS, long cBS, int nxs)
{
    constexpr int NJ = (TN == 128) ? 4 : 2;
    __shared__ u16 As[3][128 * 32];
    __shared__ u16 Bs[3][TN * 32];
    const int tid  = threadIdx.x;
    const int lane = tid & 63;
    const int bid  = blockIdx.x;
    int xq, yq, zq;
    if (MODE == 1) {
        zq = bid & 7;
        const int i = bid >> 3;
        xq = i & ((1 << nxs) - 1);
        yq = i >> nxs;
    } else {
        zq = 0;
        const int q = bid & 7, i = bid >> 3;
        yq = q * 8 + (i & 7);
        xq = i >> 3;
    }
    const int m0   = yq * 128;
    const int n0   = xq * TN;
    const int wm   = ((tid >> 7) & 1) * 64;
    const int wn   = ((tid >> 6) & 1) * (TN / 2);
    const int l15  = lane & 15;
    const int lg   = lane >> 4;
    const u16* Ab = A + (long)zq * aBS;
    const u16* Bb = B + (long)zq * bBS;

    f32x4 acc[4][NJ] = {};
    const int nt = K >> 5;

    // staging: thread-chunk u holds LDS bytes u*16.. (linear dest); the data
    // placed there is global chunk (r = u>>2, c = (u&3) ^ swz(r)).
    auto stage = [&](int s, int t) {
        const int u0 = tid, u1 = tid + 256;
        const int r0 = u0 >> 2, c0 = (u0 & 3) ^ ((r0 ^ (r0 >> 2)) & 3);
        const int r1 = u1 >> 2, c1 = (u1 & 3) ^ ((r1 ^ (r1 >> 2)) & 3);
        GLOAD_LDS(Ab + (long)(m0 + r0) * lda + t * 32 + c0 * 8, &As[s][u0 * 8]);
        GLOAD_LDS(Ab + (long)(m0 + r1) * lda + t * 32 + c1 * 8, &As[s][u1 * 8]);
        GLOAD_LDS(Bb + (long)(n0 + r0) * ldb + t * 32 + c0 * 8, &Bs[s][u0 * 8]);
        if (TN == 128)
            GLOAD_LDS(Bb + (long)(n0 + r1) * ldb + t * 32 + c1 * 8, &Bs[s][u1 * 8]);
    };

    // fragment-read chunk: rows are base+l15 with base multiple of 16, so
    // swz(row) = (l15 ^ (l15>>2)) & 3 for every i/j.
    const int lgs = lg ^ ((l15 ^ (l15 >> 2)) & 3);

    stage(0, 0);
    if (nt > 1) stage(1, 1);
    int cur = 0;
    for (int t = 0; t < nt; ++t) {
        if (t + 1 < nt) {
            if (TN == 128) asm volatile("s_waitcnt vmcnt(4) lgkmcnt(0)" ::: "memory");
            else           asm volatile("s_waitcnt vmcnt(3) lgkmcnt(0)" ::: "memory");
        } else {
            asm volatile("s_waitcnt vmcnt(0) lgkmcnt(0)" ::: "memory");
        }
        __builtin_amdgcn_s_barrier();
        s16x8 af[4], bg[NJ];
        #pragma unroll
        for (int i = 0; i < 4; ++i)
            af[i] = *(const s16x8*)&As[cur][(wm + i * 16 + l15) * 32 + lgs * 8];
        #pragma unroll
        for (int j = 0; j < NJ; ++j)
            bg[j] = *(const s16x8*)&Bs[cur][(wn + j * 16 + l15) * 32 + lgs * 8];
        if (t + 2 < nt) stage(cur == 0 ? 2 : cur - 1, t + 2);  // (cur+2)%3
        #pragma unroll
        for (int i = 0; i < 4; ++i)
            #pragma unroll
            for (int j = 0; j < NJ; ++j)
                acc[i][j] = __builtin_amdgcn_mfma_f32_16x16x32_bf16(bg[j], af[i], acc[i][j], 0, 0, 0);
        cur = (cur == 2) ? 0 : cur + 1;
    }

    const long cb0 = (long)zq * cBS;
    #pragma unroll
    for (int i = 0; i < 4; ++i) {
        const int row = m0 + wm + i * 16 + l15;
        float rm = 1.f;
        if ((EPI == 3 || EPI == 4) && mask) rm = mask[zq * M + row];
        #pragma unroll
        for (int j = 0; j < NJ; ++j) {
            const int nb = n0 + wn + j * 16 + lg * 4;
            if (nb >= N) continue;
            const long idx = cb0 + (long)row * ldc + nb;
            if (EPI == 0) {
                *(float4*)&Cf[idx] = make_float4(acc[i][j][0], acc[i][j][1], acc[i][j][2], acc[i][j][3]);
            } else {
                float x[4];
                if (EPI == 2) {
                    const float4 cv = *(const float4*)&Cf[idx];
                    x[0] = fmaxf(acc[i][j][0] + cv.x + bias[nb + 0], 0.f);
                    x[1] = fmaxf(acc[i][j][1] + cv.y + bias[nb + 1], 0.f);
                    x[2] = fmaxf(acc[i][j][2] + cv.z + bias[nb + 2], 0.f);
                    x[3] = fmaxf(acc[i][j][3] + cv.w + bias[nb + 3], 0.f);
                } else if (EPI == 3) {
                    const int bb0 = biasBStride ? ((zq * M + row) >> 10) * biasBStride : 0;
                    #pragma unroll
                    for (int r = 0; r < 4; ++r) {
                        float v = fmaxf(acc[i][j][r] + bias[bb0 + nb + r], 0.f);
                        x[r] = mask ? v * rm : v;
                    }
                } else if (EPI == 4) {
                    #pragma unroll
                    for (int r = 0; r < 4; ++r)
                        x[r] = acc[i][j][r] * rm * mask[zq * N + nb + r];
                } else if (EPI == 5) {
                    #pragma unroll
                    for (int r = 0; r < 4; ++r) x[r] = acc[i][j][r];
                } else {
                    const u64 pv = *(const u64*)&prev2[(long)zq * pBS + (long)row * ldp + nb];
                    #pragma unroll
                    for (int r = 0; r < 4; ++r)
                        x[r] = 2.f * acc[i][j][r] - b2f((u16)(pv >> (16 * r)));
                }
                u64 pk = (u64)f2b(x[0]) | ((u64)f2b(x[1]) << 16)
                       | ((u64)f2b(x[2]) << 32) | ((u64)f2b(x[3]) << 48);
                *(u64*)&Cb[idx] = pk;
            }
        }
    }
}

// ---------------------------------------------------------------------------
// all 11 weight conversions (fp32 [K][N] -> bf16 [n][ldD], zero-padded) in ONE
// dispatch: flat block id -> job lookup via cumulative block counts.
// ---------------------------------------------------------------------------
struct CvtJobs {
    const float* src[11];
    u16* dst[11];
    int K[11], N[11], Kpad[11], ldD[11];
    long sBS[11], dBS[11];
    int gx[11], gy[11];
    int cum[12];
};

__global__ void cvtT_all(CvtJobs J)
{
    __shared__ float t[32][33];
    const int bid = blockIdx.x;
    int j = 0;
    #pragma unroll
    for (int q = 0; q < 11; ++q) if (bid >= J.cum[q + 1]) j = q + 1;
    const int local = bid - J.cum[j];
    const int bx = local % J.gx[j];
    const int rem = local / J.gx[j];
    const int by = rem % J.gy[j];
    const int bz = rem / J.gy[j];
    const float* src = J.src[j] + (long)bz * J.sBS[j];
    u16* dst = J.dst[j] + (long)bz * J.dBS[j];
    const int K = J.K[j], N = J.N[j], Kpad = J.Kpad[j], ldD = J.ldD[j];
    const int tx = threadIdx.x, ty = threadIdx.y;
    const int k0 = bx * 32, n0 = by * 32;
    #pragma unroll
    for (int rr = ty; rr < 32; rr += 8) {
        int k = k0 + rr, n = n0 + tx;
        t[rr][tx] = (k < K && n < N) ? src[(long)k * N + n] : 0.f;
    }
    __syncthreads();
    #pragma unroll
    for (int rr = ty; rr < 32; rr += 8) {
        int n = n0 + rr, k = k0 + tx;
        if (n < N && k < Kpad) dst[(long)n * ldD + k] = f2b(t[tx][rr]);
    }
}

// bf16 [R][C] (row stride lds_) -> bf16 [C][R] (row stride ldd_), batched.
// 64x64 tiles, u64 (4xbf16) loads and stores; LDS pad 2 -> <=2-way conflicts.
__global__ __launch_bounds__(256)
void tranb64_k(const u16* __restrict__ src, u16* __restrict__ dst,
               int lds_, int ldd_, long sBS, long dBS)
{
    __shared__ u16 t[64][66];
    const int tid = threadIdx.x;
    const int r0 = blockIdx.y * 64, c0 = blockIdx.x * 64;
    src += (long)blockIdx.z * sBS;
    dst += (long)blockIdx.z * dBS;
    #pragma unroll
    for (int q = 0; q < 4; ++q) {
        const int lin = tid + q * 256;
        const int row = lin >> 4, c4 = (lin & 15) * 4;
        const u64 v = *(const u64*)&src[(long)(r0 + row) * lds_ + c0 + c4];
        t[row][c4 + 0] = (u16)(v);
        t[row][c4 + 1] = (u16)(v >> 16);
        t[row][c4 + 2] = (u16)(v >> 32);
        t[row][c4 + 3] = (u16)(v >> 48);
    }
    __syncthreads();
    #pragma unroll
    for (int q = 0; q < 4; ++q) {
        const int lin = tid + q * 256;
        const int col = lin >> 4, r4 = (lin & 15) * 4;
        u64 v = (u64)t[r4 + 0][col] | ((u64)t[r4 + 1][col] << 16)
              | ((u64)t[r4 + 2][col] << 32) | ((u64)t[r4 + 3][col] << 48);
        *(u64*)&dst[(long)(c0 + col) * ldd_ + r0 + r4] = v;
    }
}

// fused mask + fp32->bf16 convert: one block per node row
__global__ void maskcvt_k(const float* __restrict__ inp, u16* __restrict__ xbf,
                          float* __restrict__ mask)
{
    const int row = blockIdx.x, tid = threadIdx.x;
    const long base = (long)row * 1024 + tid * 4;
    float4 v = *(const float4*)&inp[base];
    u64 pk = (u64)f2b(v.x) | ((u64)f2b(v.y) << 16)
           | ((u64)f2b(v.z) << 32) | ((u64)f2b(v.w) << 48);
    *(u64*)&xbf[base] = pk;
    float s = v.x + v.y + v.z + v.w;
    __shared__ float red[256];
    red[tid] = s; __syncthreads();
    for (int o = 128; o > 0; o >>= 1) { if (tid < o) red[tid] += red[tid + o]; __syncthreads(); }
    if (tid == 0) mask[row] = (red[0] != 0.f) ? 1.f : 0.f;
}

__global__ void zero_k(float* __restrict__ p, int n)
{
    const int i = blockIdx.x * 256 + threadIdx.x;
    if (i < n) p[i] = 0.f;
}

// partial column sums of fea into mean (pre-zeroed), 64 blocks
__global__ void colmean_k(const u16* __restrict__ fea, float* __restrict__ mean)
{
    const int b = blockIdx.y, ch = blockIdx.x, f = threadIdx.x;   // 512
    const u16* p = fea + (long)b * 1024 * 512 + (long)ch * 128 * 512 + f;
    float s = 0.f;
    #pragma unroll 4
    for (int n = 0; n < 128; ++n) s += b2f(p[n * 512]);
    atomicAdd(&mean[b * 512 + f], s);
}

// c = relu((colsum/numel) @ Wc + bc), grid 8, 512 threads
__global__ void cvec8_k(const float* __restrict__ mean, const float* __restrict__ mask,
                        const float* __restrict__ Wc, const float* __restrict__ bc,
                        float* __restrict__ c)
{
    const int b = blockIdx.x, tid = threadIdx.x;
    __shared__ float red[512];
    __shared__ float mn[512];
    red[tid] = mask[b * 1024 + tid] + mask[b * 1024 + 512 + tid];
    __syncthreads();
    for (int o = 256; o > 0; o >>= 1) { if (tid < o) red[tid] += red[tid + o]; __syncthreads(); }
    const float numel = red[0];
    __syncthreads();
    mn[tid] = mean[b * 512 + tid] / numel;
    __syncthreads();
    const int o = tid & 127, q = tid >> 7;
    float cs = 0.f;
    #pragma unroll 8
    for (int f = q * 128; f < q * 128 + 128; ++f) cs += mn[f] * Wc[f * 128 + o];
    red[tid] = cs;
    __syncthreads();
    if (tid < 256) red[tid] += red[tid + 256];
    __syncthreads();
    if (tid < 128) c[b * 128 + tid] = fmaxf(red[tid] + red[tid + 128] + bc[tid], 0.f);
}

// cb[b][o] = ba1[o] + sum_j c[b][j]*Wa1[512+j][o]; grid (8 oc-chunks, 8 batch)
__global__ void cb64_k(const float* __restrict__ c, const float* __restrict__ Wa1,
                       const float* __restrict__ ba1, float* __restrict__ cb)
{
    const int oc = blockIdx.x, b = blockIdx.y, tid = threadIdx.x;  // 256
    __shared__ float cC[128];
    __shared__ float red[256];
    if (tid < 128) cC[tid] = c[b * 128 + tid];
    __syncthreads();
    const int o = tid & 63, part = tid >> 6;     // 4 partials per output
    const float* w = Wa1 + (long)(512 + part * 32) * 512 + oc * 64 + o;
    float s = 0.f;
    #pragma unroll 8
    for (int j = 0; j < 32; ++j) s += cC[part * 32 + j] * w[j * 512];
    red[tid] = s;
    __syncthreads();
    if (tid < 64) {
        float tot = red[tid] + red[tid + 64] + red[tid + 128] + red[tid + 192]
                  + ba1[oc * 64 + tid];
        cb[b * 512 + oc * 64 + tid] = tot;
    }
}

__global__ void dinv_k(const u16* __restrict__ Abf, float* __restrict__ dinv)
{
    const int row = blockIdx.x, tid = threadIdx.x;
    const u16* p = Abf + (long)row * 1024 + tid * 4;
    float s = b2f(p[0]) + b2f(p[1]) + b2f(p[2]) + b2f(p[3]);
    __shared__ float red[256];
    red[tid] = s; __syncthreads();
    for (int o = 128; o > 0; o >>= 1) { if (tid < o) red[tid] += red[tid + o]; __syncthreads(); }
    if (tid == 0) {
        float d = red[0];
        dinv[row] = d > 0.f ? rsqrtf(fmaxf(d, 1e-30f)) : 0.f;
    }
}

__global__ void lhat_k(u16* __restrict__ Abf, const float* __restrict__ dinv)
{
    const long e0 = ((long)blockIdx.x * 256 + threadIdx.x) * 4;
    const int b = (int)(e0 >> 20);
    const int i = (int)((e0 >> 10) & 1023);
    const int j = (int)(e0 & 1023);
    const float di = dinv[b * 1024 + i];
    u16* p = Abf + e0;
    #pragma unroll
    for (int t = 0; t < 4; ++t) {
        float v = -di * b2f(p[t]) * dinv[b * 1024 + j + t];
        p[t] = f2b(v);
    }
}

__global__ void gate_k(const u16* __restrict__ g2, const float* __restrict__ Wp3,
                       const float* __restrict__ bp3, const float* __restrict__ mask,
                       float* __restrict__ gate)
{
    const int row = blockIdx.x * 4 + (threadIdx.x >> 6);
    const int lane = threadIdx.x & 63;
    float v = b2f(g2[row * 64 + lane]) * Wp3[lane];
    for (int o = 32; o > 0; o >>= 1) v += __shfl_xor(v, o, 64);
    if (lane == 0)
        gate[row] = (mask[row] > 0.f) ? tanhf(v + bp3[0]) : -1e9f;
}

// per-batch softmax over 1024 gates -> att
__global__ void attw_k(const float* __restrict__ gate, float* __restrict__ att)
{
    const int b = blockIdx.x, tid = threadIdx.x;  // 256
    const float* g = gate + b * 1024;
    float4 v = *(const float4*)&g[tid * 4];
    __shared__ float red[256];
    red[tid] = fmaxf(fmaxf(v.x, v.y), fmaxf(v.z, v.w));
    __syncthreads();
    for (int o = 128; o > 0; o >>= 1) { if (tid < o) red[tid] = fmaxf(red[tid], red[tid + o]); __syncthreads(); }
    const float mx = red[0];
    __syncthreads();
    float e0 = expf(v.x - mx), e1 = expf(v.y - mx), e2 = expf(v.z - mx), e3 = expf(v.w - mx);
    red[tid] = e0 + e1 + e2 + e3;
    __syncthreads();
    for (int o = 128; o > 0; o >>= 1) { if (tid < o) red[tid] += red[tid + o]; __syncthreads(); }
    const float zi = 1.f / red[0];
    float4 w = { e0 * zi, e1 * zi, e2 * zi, e3 * zi };
    *(float4*)&att[b * 1024 + tid * 4] = w;
}

// partial weighted sums into pooled (pre-zeroed), 64 blocks
__global__ void wsum_k(const float* __restrict__ att, const u16* __restrict__ x2,
                       float* __restrict__ pooled)
{
    const int b = blockIdx.y, ch = blockIdx.x, o = threadIdx.x;  // 384
    const u16* xb = x2 + (long)b * 1024 * 384 + (long)ch * 128 * 384 + o;
    const float* ab = att + b * 1024 + ch * 128;
    float s = 0.f;
    #pragma unroll 4
    for (int n = 0; n < 128; ++n) s += ab[n] * b2f(xb[n * 384]);
    atomicAdd(&pooled[b * 384 + o], s);
}

// output MLP, one block per batch
__global__ void final8_k(const float* __restrict__ pooled, const float* __restrict__ Wm1,
                         const float* __restrict__ bm1, const float* __restrict__ Wm2,
                         const float* __restrict__ bm2, float* __restrict__ out)
{
    __shared__ float pl[384];
    __shared__ float wred[4];
    const int b = blockIdx.x, tid = threadIdx.x;  // 256
    if (tid < 192) {
        pl[tid] = pooled[b * 384 + tid];
        pl[tid + 192] = pooled[b * 384 + tid + 192];
    }
    __syncthreads();
    float s = bm1[tid];
    for (int f = 0; f < 384; ++f) s += pl[f] * Wm1[f * 256 + tid];
    float h = fmaxf(s, 0.f) * Wm2[tid];
    for (int off = 32; off > 0; off >>= 1) h += __shfl_xor(h, off, 64);
    if ((tid & 63) == 0) wred[tid >> 6] = h;
    __syncthreads();
    if (tid == 0)
        out[b] = 1.f / (1.f + expf(-(wred[0] + wred[1] + wred[2] + wred[3] + bm2[0])));
}

// ---------------------------------------------------------------------------
// workspace layout
// ---------------------------------------------------------------------------
constexpr size_t OFS_WF1T = 0;                               // 832x1024 bf16
constexpr size_t OFS_WF2T = OFS_WF1T + 832ull * 1024 * 2;    // 512x800
constexpr size_t OFS_WF3T = OFS_WF2T + 512ull * 800 * 2;     // 512x512
constexpr size_t OFS_WA1T = OFS_WF3T + 512ull * 512 * 2;
constexpr size_t OFS_WA2T = OFS_WA1T + 512ull * 512 * 2;     // 384x512
constexpr size_t OFS_WG1T0 = OFS_WA2T + 384ull * 512 * 2;    // 512x512
constexpr size_t OFS_WG1C  = OFS_WG1T0 + 512ull * 512 * 2;   // 512x2048
constexpr size_t OFS_WG2T0 = OFS_WG1C + 512ull * 2048 * 2;   // 384x512
constexpr size_t OFS_WG2C  = OFS_WG2T0 + 384ull * 512 * 2;   // 384x2048
constexpr size_t OFS_WP1T  = OFS_WG2C + 384ull * 2048 * 2;   // 128x384
constexpr size_t OFS_WP2T  = OFS_WP1T + 128ull * 384 * 2;    // 64x128
constexpr size_t OFS_MASK  = OFS_WP2T + 64ull * 128 * 2;
constexpr size_t OFS_MEAN  = OFS_MASK + 32768;
constexpr size_t OFS_CVEC  = OFS_MEAN + 16384;
constexpr size_t OFS_CB    = OFS_CVEC + 4096;
constexpr size_t OFS_DINV  = OFS_CB + 16384;
constexpr size_t OFS_GATE  = OFS_DINV + 32768;
constexpr size_t OFS_ATT   = OFS_GATE + 32768;
constexpr size_t OFS_POOL  = OFS_ATT + 32768;
constexpr size_t OFS_RA    = OFS_POOL + 16384;               // 16 MiB: xbf | a1,a2 | facc
constexpr size_t OFS_RB    = OFS_RA + 16777216;              // 12.5 MiB: h1 | tt
constexpr size_t OFS_RC    = OFS_RB + 13107200;              // 8 MiB: h2 | x1 | g1,g2
constexpr size_t OFS_RD    = OFS_RC + 8388608;               // 8 MiB: fea | x2
constexpr size_t OFS_RE    = OFS_RD + 8388608;               // 16 MiB: abf (Lhat)
constexpr size_t OFS_RF    = OFS_RE + 16777216;              // 32 MiB: Tcat (T1..T4)
constexpr size_t WS_TOTAL  = OFS_RF + 33554432;              // ~100.9 MiB

extern "C" void kernel_launch(void* const* d_in, const int* in_sizes, int n_in,
                              void* d_out, int out_size, void* d_ws, size_t ws_size,
                              hipStream_t stream)
{
    const float* inp = (const float*)d_in[0];
    const float* Wf1 = (const float*)d_in[2];  const float* bf1 = (const float*)d_in[3];
    const float* Wf2 = (const float*)d_in[4];  const float* bf2 = (const float*)d_in[5];
    const float* Wf3 = (const float*)d_in[6];  const float* bf3 = (const float*)d_in[7];
    const float* Wc  = (const float*)d_in[8];  const float* bc  = (const float*)d_in[9];
    const float* Wa1 = (const float*)d_in[10]; const float* ba1 = (const float*)d_in[11];
    const float* Wa2 = (const float*)d_in[12]; const float* ba2 = (const float*)d_in[13];
    const float* Wg1 = (const float*)d_in[14]; const float* bg1 = (const float*)d_in[15];
    const float* Wg2 = (const float*)d_in[16]; const float* bg2 = (const float*)d_in[17];
    const float* Wp1 = (const float*)d_in[18]; const float* bp1 = (const float*)d_in[19];
    const float* Wp2 = (const float*)d_in[20]; const float* bp2 = (const float*)d_in[21];
    const float* Wp3 = (const float*)d_in[22]; const float* bp3 = (const float*)d_in[23];
    const float* Wm1 = (const float*)d_in[24]; const float* bm1 = (const float*)d_in[25];
    const float* Wm2 = (const float*)d_in[26]; const float* bm2 = (const float*)d_in[27];

    if (ws_size < WS_TOTAL) return;
    char* ws = (char*)d_ws;

    u16* wf1t  = (u16*)(ws + OFS_WF1T);
    u16* wf2t  = (u16*)(ws + OFS_WF2T);
    u16* wf3t  = (u16*)(ws + OFS_WF3T);
    u16* wa1t  = (u16*)(ws + OFS_WA1T);
    u16* wa2t  = (u16*)(ws + OFS_WA2T);
    u16* wg1t0 = (u16*)(ws + OFS_WG1T0);
    u16* wg1c  = (u16*)(ws + OFS_WG1C);
    u16* wg2t0 = (u16*)(ws + OFS_WG2T0);
    u16* wg2c  = (u16*)(ws + OFS_WG2C);
    u16* wp1t  = (u16*)(ws + OFS_WP1T);
    u16* wp2t  = (u16*)(ws + OFS_WP2T);
    float* maskv   = (float*)(ws + OFS_MASK);
    float* meanv   = (float*)(ws + OFS_MEAN);
    float* cvecv   = (float*)(ws + OFS_CVEC);
    float* cbv     = (float*)(ws + OFS_CB);
    float* dinvv   = (float*)(ws + OFS_DINV);
    float* gatev   = (float*)(ws + OFS_GATE);
    float* attv    = (float*)(ws + OFS_ATT);
    float* pooledv = (float*)(ws + OFS_POOL);

    u16*   xbf  = (u16*)(ws + OFS_RA);
    u16*   a1b  = (u16*)(ws + OFS_RA);                 // after f1
    u16*   a2b  = (u16*)(ws + OFS_RA + 8388608);
    float* facc = (float*)(ws + OFS_RA);               // after adjm
    u16*   h1   = (u16*)(ws + OFS_RB);
    u16*   tt   = (u16*)(ws + OFS_RB);                 // after f2
    u16*   h2   = (u16*)(ws + OFS_RC);
    u16*   x1   = (u16*)(ws + OFS_RC);                 // after f3
    u16*   g1   = (u16*)(ws + OFS_RC);                 // after cheb2
    u16*   g2   = (u16*)(ws + OFS_RC + 2097152);
    u16*   fea  = (u16*)(ws + OFS_RD);
    u16*   x2   = (u16*)(ws + OFS_RD);                 // after cheb1
    u16*   abf  = (u16*)(ws + OFS_RE);
    u16*   tcat = (u16*)(ws + OFS_RF);                 // [8192][2048] = T1..T4

    // ---- all weight conversions in one dispatch -----------------------------
    CvtJobs J;
    auto setjob = [&](int i, const float* s, u16* d, int K, int N, int Kp, int ld,
                      long sb, long db, int gx, int gy, int gz) {
        J.src[i] = s; J.dst[i] = d; J.K[i] = K; J.N[i] = N; J.Kpad[i] = Kp; J.ldD[i] = ld;
        J.sBS[i] = sb; J.dBS[i] = db; J.gx[i] = gx; J.gy[i] = gy;
        J.cum[i + 1] = J.cum[i] + gx * gy * gz;
    };
    J.cum[0] = 0;
    setjob(0,  Wf1, wf1t, 1024, 784, 1024, 1024, 0, 0, 32, 25, 1);
    setjob(1,  Wf2, wf2t, 784, 512, 800, 800, 0, 0, 25, 16, 1);
    setjob(2,  Wf3, wf3t, 512, 512, 512, 512, 0, 0, 16, 16, 1);
    setjob(3,  Wa1, wa1t, 512, 512, 512, 512, 0, 0, 16, 16, 1);
    setjob(4,  Wa2, wa2t, 512, 384, 512, 512, 0, 0, 16, 12, 1);
    setjob(5,  Wg1, wg1t0, 512, 512, 512, 512, 0, 0, 16, 16, 1);
    setjob(6,  Wg1 + 262144, wg1c, 512, 512, 512, 2048, 262144, 512, 16, 16, 4);
    setjob(7,  Wg2, wg2t0, 512, 384, 512, 512, 0, 0, 16, 12, 1);
    setjob(8,  Wg2 + 196608, wg2c, 512, 384, 512, 2048, 196608, 512, 16, 12, 4);
    setjob(9,  Wp1, wp1t, 384, 128, 384, 384, 0, 0, 12, 4, 1);
    setjob(10, Wp2, wp2t, 128, 64, 128, 128, 0, 0, 4, 2, 1);
    cvtT_all<<<J.cum[11], dim3(32, 8), 0, stream>>>(J);

    maskcvt_k<<<8192, 256, 0, stream>>>(inp, xbf, maskv);

    // fe_extrator  (MODE 2: weight GEMMs, y-partitioned per XCD)
    gemm_bt<3, 64, 2><<<13 * 64, 256, 0, stream>>>(xbf, wf1t, nullptr, h1, bf1, 0, maskv,
        nullptr, 0, 0, 8192, 784, 1024, 1024, 1024, 800, 0, 0, 0, 0);
    gemm_bt<3, 64, 2><<<8 * 64, 256, 0, stream>>>(h1, wf2t, nullptr, h2, bf2, 0, maskv,
        nullptr, 0, 0, 8192, 512, 800, 800, 800, 512, 0, 0, 0, 0);
    gemm_bt<3, 64, 2><<<8 * 64, 256, 0, stream>>>(h2, wf3t, nullptr, fea, bf3, 0, maskv,
        nullptr, 0, 0, 8192, 512, 512, 512, 512, 512, 0, 0, 0, 0);

    // c vector + per-batch bias for adj layer 1
    zero_k<<<16, 256, 0, stream>>>(meanv, 8 * 512);
    colmean_k<<<dim3(8, 8), 512, 0, stream>>>(fea, meanv);
    cvec8_k<<<8, 512, 0, stream>>>(meanv, maskv, Wc, bc, cvecv);
    cb64_k<<<dim3(8, 8), 256, 0, stream>>>(cvecv, Wa1, ba1, cbv);

    // adj net
    gemm_bt<3, 64, 2><<<8 * 64, 256, 0, stream>>>(fea, wa1t, nullptr, a1b, cbv, 512, maskv,
        nullptr, 0, 0, 8192, 512, 512, 512, 512, 512, 0, 0, 0, 0);
    gemm_bt<3, 64, 2><<<6 * 64, 256, 0, stream>>>(a1b, wa2t, nullptr, a2b, ba2, 0, maskv,
        nullptr, 0, 0, 8192, 384, 512, 512, 512, 384, 0, 0, 0, 0);

    // adjacency, degree, Lhat (in place)  (MODE 1: batch z pinned to XCD z)
    gemm_bt<4, 64, 1><<<8 * 16 * 8, 256, 0, stream>>>(a2b, a2b, nullptr, abf, nullptr, 0, maskv,
        nullptr, 0, 0, 1024, 1024, 384, 384, 384, 1024, 393216, 393216, 1048576, 4);
    dinv_k<<<8192, 256, 0, stream>>>(abf, dinvv);
    lhat_k<<<8192, 256, 0, stream>>>(abf, dinvv);

    // ChebConv: T0 separate, T1..T4 K-concat in tcat; out = T0@W0 + Tcat@Wcat + b
    auto cheb = [&](const u16* T0, const u16* W0, const u16* Wcat, int Wn,
                    const float* bias, u16* outb, float* fa) {
        const int gL = 8 * 8 * 8;     // MODE 1, nxs=3 (8 n-blocks), 8 m-blocks
        const dim3 gT0(8, 16, 8);     // transpose [1024][512] per batch
        const dim3 gTc(8, 16, 8);     // transpose [1024][512] slice of tcat
        // tt = T0^T
        tranb64_k<<<gT0, 256, 0, stream>>>(T0, tt, 512, 1024, 524288, 524288);
        // T1 = Lhat @ T0
        gemm_bt<5, 64, 1><<<gL, 256, 0, stream>>>(abf, tt, nullptr, tcat, nullptr, 0, nullptr,
            nullptr, 0, 0, 1024, 512, 1024, 1024, 1024, 2048, 1048576, 524288, 2097152, 3);
        tranb64_k<<<gTc, 256, 0, stream>>>(tcat, tt, 2048, 1024, 2097152, 524288);
        // T2 = 2 Lhat T1 - T0
        gemm_bt<6, 64, 1><<<gL, 256, 0, stream>>>(abf, tt, nullptr, tcat + 512, nullptr, 0, nullptr,
            T0, 512, 524288, 1024, 512, 1024, 1024, 1024, 2048, 1048576, 524288, 2097152, 3);
        tranb64_k<<<gTc, 256, 0, stream>>>(tcat + 512, tt, 2048, 1024, 2097152, 524288);
        // T3 = 2 Lhat T2 - T1
        gemm_bt<6, 64, 1><<<gL, 256, 0, stream>>>(abf, tt, nullptr, tcat + 1024, nullptr, 0, nullptr,
            tcat, 2048, 2097152, 1024, 512, 1024, 1024, 1024, 2048, 1048576, 524288, 2097152, 3);
        tranb64_k<<<gTc, 256, 0, stream>>>(tcat + 1024, tt, 2048, 1024, 2097152, 524288);
        // T4 = 2 Lhat T3 - T2
        gemm_bt<6, 64, 1><<<gL, 256, 0, stream>>>(abf, tt, nullptr, tcat + 1536, nullptr, 0, nullptr,
            tcat + 512, 2048, 2097152, 1024, 512, 1024, 1024, 1024, 2048, 1048576, 524288, 2097152, 3);
        // facc = T0 @ W0 ; out = relu(facc + Tcat @ Wcat + bias)
        gemm_bt<0, 64, 2><<<(Wn / 64) * 64, 256, 0, stream>>>(T0, W0, fa, nullptr, nullptr, 0,
            nullptr, nullptr, 0, 0, 8192, Wn, 512, 512, 512, Wn, 0, 0, 0, 0);
        gemm_bt<2, 64, 2><<<(Wn / 64) * 64, 256, 0, stream>>>(tcat, Wcat, fa, outb, bias, 0,
            nullptr, nullptr, 0, 0, 8192, Wn, 2048, 2048, 2048, Wn, 0, 0, 0, 0);
    };

    cheb(fea, wg1t0, wg1c, 512, bg1, x1, facc);
    cheb(x1,  wg2t0, wg2c, 384, bg2, x2, facc);

    // attention gate net + pooling tail
    gemm_bt<3, 64, 2><<<2 * 64, 256, 0, stream>>>(x2, wp1t, nullptr, g1, bp1, 0, nullptr,
        nullptr, 0, 0, 8192, 128, 384, 384, 384, 128, 0, 0, 0, 0);
    gemm_bt<3, 64, 2><<<1 * 64, 256, 0, stream>>>(g1, wp2t, nullptr, g2, bp2, 0, nullptr,
        nullptr, 0, 0, 8192, 64, 128, 128, 128, 64, 0, 0, 0, 0);
    gate_k<<<2048, 256, 0, stream>>>(g2, Wp3, bp3, maskv, gatev);
    attw_k<<<8, 256, 0, stream>>>(gatev, attv);
    zero_k<<<12, 256, 0, stream>>>(pooledv, 8 * 384);
    wsum_k<<<dim3(8, 8), 384, 0, stream>>>(attv, x2, pooledv);
    final8_k<<<8, 256, 0, stream>>>(pooledv, Wm1, bm1, Wm2, bm2, (float*)d_out);
}